// Round 4
// baseline (2196.893 us; speedup 1.0000x reference)
//
#include <hip/hip_runtime.h>
#include <cstdint>
#include <cstddef>

#define NN 30000
#define NE 60000
#define NG 1200
#define HID 384
#define EMB 768
#define OUTD 768
#define NEGS 0.01f

typedef _Float16 f16;
typedef _Float16 f16x8 __attribute__((ext_vector_type(8)));
typedef float f32x16 __attribute__((ext_vector_type(16)));

static __device__ __forceinline__ float leaky(float x){ return x > 0.f ? x : NEGS * x; }
static __device__ __forceinline__ float elu1(float x){ return x > 0.f ? x : (expf(x) - 1.f); }
static __device__ __forceinline__ float sigm(float x){ return 1.f / (1.f + expf(-x)); }

static __device__ __forceinline__ void atomicMaxF(float* a, float v){
  if (v >= 0.f) atomicMax((int*)a, __float_as_int(v));
  else atomicMin((unsigned int*)a, __float_as_uint(v));
}

// ---------------- f32 tiled GEMM (kept for small/G-sized ops) ----------------
__global__ __launch_bounds__(256) void k_gemm(
    const float* __restrict__ A, const float* __restrict__ B,
    const float* __restrict__ bias, float* __restrict__ C,
    int M, int N, int K, int act)
{
  __shared__ float As[16][65];
  __shared__ float Bs[16][65];
  const int tid = threadIdx.x;
  const int tx = tid & 15, ty = tid >> 4;
  const int row0 = blockIdx.y * 64, col0 = blockIdx.x * 64;
  const int ar = tid >> 2, ak = (tid & 3) << 2;
  const int bk = tid >> 4, bc = (tid & 15) << 2;
  float acc[4][4] = {};
  for (int k0 = 0; k0 < K; k0 += 16) {
    float4 av = make_float4(0.f, 0.f, 0.f, 0.f);
    if (row0 + ar < M)
      av = *(const float4*)(A + (size_t)(row0 + ar) * K + k0 + ak);
    As[ak + 0][ar] = av.x; As[ak + 1][ar] = av.y;
    As[ak + 2][ar] = av.z; As[ak + 3][ar] = av.w;
    float4 bv = *(const float4*)(B + (size_t)(k0 + bk) * N + col0 + bc);
    Bs[bk][bc + 0] = bv.x; Bs[bk][bc + 1] = bv.y;
    Bs[bk][bc + 2] = bv.z; Bs[bk][bc + 3] = bv.w;
    __syncthreads();
#pragma unroll
    for (int kk = 0; kk < 16; kk++) {
      float a[4], b[4];
#pragma unroll
      for (int i = 0; i < 4; i++) a[i] = As[kk][(ty << 2) + i];
#pragma unroll
      for (int j = 0; j < 4; j++) b[j] = Bs[kk][(tx << 2) + j];
#pragma unroll
      for (int i = 0; i < 4; i++)
#pragma unroll
        for (int j = 0; j < 4; j++)
          acc[i][j] = fmaf(a[i], b[j], acc[i][j]);
    }
    __syncthreads();
  }
#pragma unroll
  for (int i = 0; i < 4; i++) {
    int r = row0 + (ty << 2) + i;
    if (r >= M) continue;
#pragma unroll
    for (int j = 0; j < 4; j++) {
      int c = col0 + (tx << 2) + j;
      float v = acc[i][j];
      if (bias) v += bias[c];
      if (act == 1) v = leaky(v);
      else if (act == 2) v = elu1(v);
      else if (act == 3) v = fmaxf(v, 0.f);
      C[(size_t)r * N + c] = v;
    }
  }
}

// ------------- f32 fused GRU GEMM (kept for G-sized mol loop) -------------
__global__ __launch_bounds__(256) void k_gru_gemm(
    const float* __restrict__ U, const float* __restrict__ Hs,
    const float* __restrict__ Wi, const float* __restrict__ Wh,
    const float* __restrict__ bi, const float* __restrict__ bh,
    float* __restrict__ Xo, int M)
{
  __shared__ float Us[16][65];
  __shared__ float Hss[16][65];
  __shared__ float Bis[3][16][65];
  __shared__ float Bhs[3][16][65];
  const int tid = threadIdx.x;
  const int tx = tid & 15, ty = tid >> 4;
  const int row0 = blockIdx.y * 64, col0 = blockIdx.x * 64;
  const int ar = tid >> 2, ak = (tid & 3) << 2;
  const int bk = tid >> 4, bc = (tid & 15) << 2;
  float aR[4][4] = {}, aZ[4][4] = {}, aN_[4][4] = {};
  float hR[4][4] = {}, hZ[4][4] = {}, hN[4][4] = {};
  for (int k0 = 0; k0 < HID; k0 += 16) {
    float4 uv = make_float4(0.f, 0.f, 0.f, 0.f);
    float4 hv = make_float4(0.f, 0.f, 0.f, 0.f);
    if (row0 + ar < M) {
      uv = *(const float4*)(U  + (size_t)(row0 + ar) * HID + k0 + ak);
      hv = *(const float4*)(Hs + (size_t)(row0 + ar) * HID + k0 + ak);
    }
    Us[ak + 0][ar] = uv.x; Us[ak + 1][ar] = uv.y;
    Us[ak + 2][ar] = uv.z; Us[ak + 3][ar] = uv.w;
    Hss[ak + 0][ar] = hv.x; Hss[ak + 1][ar] = hv.y;
    Hss[ak + 2][ar] = hv.z; Hss[ak + 3][ar] = hv.w;
#pragma unroll
    for (int g = 0; g < 3; g++) {
      float4 bv = *(const float4*)(Wi + (size_t)(k0 + bk) * (3 * HID) + g * HID + col0 + bc);
      Bis[g][bk][bc + 0] = bv.x; Bis[g][bk][bc + 1] = bv.y;
      Bis[g][bk][bc + 2] = bv.z; Bis[g][bk][bc + 3] = bv.w;
      float4 cv = *(const float4*)(Wh + (size_t)(k0 + bk) * (3 * HID) + g * HID + col0 + bc);
      Bhs[g][bk][bc + 0] = cv.x; Bhs[g][bk][bc + 1] = cv.y;
      Bhs[g][bk][bc + 2] = cv.z; Bhs[g][bk][bc + 3] = cv.w;
    }
    __syncthreads();
#pragma unroll
    for (int kk = 0; kk < 16; kk++) {
      float au[4], ah[4];
#pragma unroll
      for (int i = 0; i < 4; i++) { au[i] = Us[kk][(ty << 2) + i]; ah[i] = Hss[kk][(ty << 2) + i]; }
      float br[4], bz[4], bn[4], cr[4], cz[4], cn[4];
#pragma unroll
      for (int j = 0; j < 4; j++) {
        br[j] = Bis[0][kk][(tx << 2) + j]; bz[j] = Bis[1][kk][(tx << 2) + j]; bn[j] = Bis[2][kk][(tx << 2) + j];
        cr[j] = Bhs[0][kk][(tx << 2) + j]; cz[j] = Bhs[1][kk][(tx << 2) + j]; cn[j] = Bhs[2][kk][(tx << 2) + j];
      }
#pragma unroll
      for (int i = 0; i < 4; i++)
#pragma unroll
        for (int j = 0; j < 4; j++) {
          aR[i][j]  = fmaf(au[i], br[j], aR[i][j]);
          aZ[i][j]  = fmaf(au[i], bz[j], aZ[i][j]);
          aN_[i][j] = fmaf(au[i], bn[j], aN_[i][j]);
          hR[i][j]  = fmaf(ah[i], cr[j], hR[i][j]);
          hZ[i][j]  = fmaf(ah[i], cz[j], hZ[i][j]);
          hN[i][j]  = fmaf(ah[i], cn[j], hN[i][j]);
        }
    }
    __syncthreads();
  }
#pragma unroll
  for (int i = 0; i < 4; i++) {
    int r = row0 + (ty << 2) + i;
    if (r >= M) continue;
#pragma unroll
    for (int j = 0; j < 4; j++) {
      int c = col0 + (tx << 2) + j;
      float rg = sigm(aR[i][j] + bi[c] + hR[i][j] + bh[c]);
      float zg = sigm(aZ[i][j] + bi[HID + c] + hZ[i][j] + bh[HID + c]);
      float ng = tanhf(aN_[i][j] + bi[2 * HID + c] + rg * (hN[i][j] + bh[2 * HID + c]));
      float o = (1.f - zg) * ng + zg * Hs[(size_t)r * HID + c];
      Xo[(size_t)r * HID + c] = fmaxf(o, 0.f);
    }
  }
}

// ------------- MFMA f16 GEMM, NO LDS: operands straight from global (L1/L2) -------------
// C = act(Ah[M,384] @ Bt[Nn][384]^T + bias). BM=128, BN=128; 4 waves 2x2, wave 64x64.
// 1D grid, XCD-grouped: blocks sharing A-rows get ids == same (mod 8).
__global__ __launch_bounds__(256) void k_hgemm(
    const f16* __restrict__ Ah, const f16* __restrict__ Bt,
    const float* __restrict__ bias, float* __restrict__ Cf, f16* __restrict__ Ch,
    int M, int Nn, int act)
{
  const int nct = Nn >> 7;                    // column tiles (Nn/128)
  const int id = blockIdx.x;
  const int lane8 = id & 7, chunk = id >> 3;
  const int ct = chunk % nct, rg = chunk / nct;
  const int rt = rg * 8 + lane8;
  const int Mt = (M + 127) >> 7;
  if (rt >= Mt) return;
  const int r0 = rt * 128, n0 = ct * 128;
  const int tid = threadIdx.x;
  const int wid = tid >> 6, lane = tid & 63;
  const int wr = wid >> 1, wc = wid & 1;
  const int l31 = lane & 31, lhi = lane >> 5;
  const f16* pA = Ah + (size_t)(r0 + wr * 64 + l31) * HID + lhi * 8;
  const f16* pB = Bt + (size_t)(n0 + wc * 64 + l31) * HID + lhi * 8;
  f32x16 acc[2][2];
#pragma unroll
  for (int i = 0; i < 2; i++)
#pragma unroll
    for (int j = 0; j < 2; j++)
#pragma unroll
      for (int r = 0; r < 16; r++) acc[i][j][r] = 0.f;
#pragma unroll 4
  for (int k0 = 0; k0 < HID; k0 += 16) {
    f16x8 af[2], bf[2];
#pragma unroll
    for (int i = 0; i < 2; i++) af[i] = *(const f16x8*)(pA + (size_t)i * 32 * HID + k0);
#pragma unroll
    for (int j = 0; j < 2; j++) bf[j] = *(const f16x8*)(pB + (size_t)j * 32 * HID + k0);
#pragma unroll
    for (int i = 0; i < 2; i++)
#pragma unroll
      for (int j = 0; j < 2; j++)
        acc[i][j] = __builtin_amdgcn_mfma_f32_32x32x16_f16(af[i], bf[j], acc[i][j], 0, 0, 0);
  }
#pragma unroll
  for (int i = 0; i < 2; i++)
#pragma unroll
    for (int j = 0; j < 2; j++) {
      int col = n0 + wc * 64 + j * 32 + l31;
      float bv = bias ? bias[col] : 0.f;
#pragma unroll
      for (int r = 0; r < 16; r++) {
        int row = r0 + wr * 64 + i * 32 + (r & 3) + 8 * (r >> 2) + 4 * lhi;
        if (row < M) {
          float v = acc[i][j][r] + bv;
          if (act == 1) v = leaky(v);
          else if (act == 2) v = elu1(v);
          else if (act == 3) v = fmaxf(v, 0.f);
          if (Cf) Cf[(size_t)row * Nn + col] = v;
          if (Ch) Ch[(size_t)row * Nn + col] = (f16)v;
        }
      }
    }
}

// ------------- MFMA f16 fused GRU, NO LDS: Xo = relu(GRU(Uh@Wi, Hsh@Wh, Hsf)) -------------
// Wit/Wht f16 [1152][384] (transposed). BM=64 rows, BN=64 gate-cols; 4 waves 2x2, wave 32x32.
__global__ __launch_bounds__(256) void k_gru_hgemm(
    const f16* __restrict__ Uh, const f16* __restrict__ Hsh, const float* __restrict__ Hsf,
    const f16* __restrict__ Wit, const f16* __restrict__ Wht,
    const float* __restrict__ bi, const float* __restrict__ bh,
    float* __restrict__ Xo, f16* __restrict__ Xoh, int M)
{
  const int id = blockIdx.x;
  const int lane8 = id & 7, chunk = id >> 3;
  const int ct = chunk % 6, rg = chunk / 6;
  const int rt = rg * 8 + lane8;
  const int Mt = (M + 63) >> 6;
  if (rt >= Mt) return;
  const int r0 = rt * 64, c0 = ct * 64;
  const int tid = threadIdx.x;
  const int wid = tid >> 6, lane = tid & 63;
  const int wr = wid >> 1, wc = wid & 1;
  const int l31 = lane & 31, lhi = lane >> 5;
  const size_t GSTRIDE = (size_t)HID * HID;   // one gate block of Wt
  const f16* pU = Uh  + (size_t)(r0 + wr * 32 + l31) * HID + lhi * 8;
  const f16* pH = Hsh + (size_t)(r0 + wr * 32 + l31) * HID + lhi * 8;
  const f16* pWi = Wit + (size_t)(c0 + wc * 32 + l31) * HID + lhi * 8;
  const f16* pWh = Wht + (size_t)(c0 + wc * 32 + l31) * HID + lhi * 8;
#define Z16 {0,0,0,0,0,0,0,0,0,0,0,0,0,0,0,0}
  f32x16 aR = Z16, aZ = Z16, aN = Z16, hR = Z16, hZ = Z16, hN = Z16;
#pragma unroll 4
  for (int k0 = 0; k0 < HID; k0 += 16) {
    f16x8 au  = *(const f16x8*)(pU + k0);
    f16x8 ah  = *(const f16x8*)(pH + k0);
    f16x8 bir = *(const f16x8*)(pWi + k0);
    f16x8 biz = *(const f16x8*)(pWi + GSTRIDE + k0);
    f16x8 bin = *(const f16x8*)(pWi + 2 * GSTRIDE + k0);
    f16x8 bhr = *(const f16x8*)(pWh + k0);
    f16x8 bhz = *(const f16x8*)(pWh + GSTRIDE + k0);
    f16x8 bhn = *(const f16x8*)(pWh + 2 * GSTRIDE + k0);
    aR = __builtin_amdgcn_mfma_f32_32x32x16_f16(au, bir, aR, 0, 0, 0);
    aZ = __builtin_amdgcn_mfma_f32_32x32x16_f16(au, biz, aZ, 0, 0, 0);
    aN = __builtin_amdgcn_mfma_f32_32x32x16_f16(au, bin, aN, 0, 0, 0);
    hR = __builtin_amdgcn_mfma_f32_32x32x16_f16(ah, bhr, hR, 0, 0, 0);
    hZ = __builtin_amdgcn_mfma_f32_32x32x16_f16(ah, bhz, hZ, 0, 0, 0);
    hN = __builtin_amdgcn_mfma_f32_32x32x16_f16(ah, bhn, hN, 0, 0, 0);
  }
  const int col = c0 + wc * 32 + l31;  // in [0, 384)
  const float bir_ = bi[col], biz_ = bi[HID + col], bin_ = bi[2 * HID + col];
  const float bhr_ = bh[col], bhz_ = bh[HID + col], bhn_ = bh[2 * HID + col];
#pragma unroll
  for (int r = 0; r < 16; r++) {
    int row = r0 + wr * 32 + (r & 3) + 8 * (r >> 2) + 4 * lhi;
    if (row < M) {
      float rg = sigm(aR[r] + hR[r] + bir_ + bhr_);
      float zg = sigm(aZ[r] + hZ[r] + biz_ + bhz_);
      float ng = tanhf(aN[r] + bin_ + rg * (hN[r] + bhn_));
      float o = (1.f - zg) * ng + zg * Hsf[(size_t)row * HID + col];
      o = fmaxf(o, 0.f);
      Xo[(size_t)row * HID + col] = o;
      Xoh[(size_t)row * HID + col] = (f16)o;
    }
  }
}

// transpose + f32->f16: Wt[n][k] = (f16) W[k][n];  W is [K][Nn]. block (32,8)
__global__ void k_wt_h(const float* __restrict__ W, f16* __restrict__ Wt, int K, int Nn)
{
  __shared__ float tile[32][33];
  const int kx = blockIdx.x * 32, nx = blockIdx.y * 32;
  const int tx = threadIdx.x, ty = threadIdx.y;
#pragma unroll
  for (int i = 0; i < 4; i++) {
    int k = kx + ty + i * 8;
    if (k < K && nx + tx < Nn) tile[ty + i * 8][tx] = W[(size_t)k * Nn + nx + tx];
  }
  __syncthreads();
#pragma unroll
  for (int i = 0; i < 4; i++) {
    int n = nx + ty + i * 8;
    if (n < Nn && kx + tx < K) Wt[(size_t)n * K + kx + tx] = (f16)tile[tx][ty + i * 8];
  }
}

// elementwise f32 -> f16
__global__ void k_f2h(const float* __restrict__ in, f16* __restrict__ out, long total)
{
  long t = (long)blockIdx.x * blockDim.x + threadIdx.x;
  if (t >= total) return;
  out[t] = (f16)in[t];
}

// x1[i,c] = leaky(sum_j T1[x_idx[i,j], c] + lin1_b[c]); dual f32+f16 out
__global__ void k_node_embed(const int* __restrict__ xi, const float* __restrict__ T1,
                             const float* __restrict__ b, float* __restrict__ x1,
                             f16* __restrict__ x1h, long total)
{
  long t = (long)blockIdx.x * blockDim.x + threadIdx.x;
  if (t >= total) return;
  int i = (int)(t / HID), c = (int)(t % HID);
  float v = b[c];
#pragma unroll
  for (int j = 0; j < 9; j++) v += T1[(size_t)xi[i * 9 + j] * HID + c];
  v = leaky(v);
  x1[t] = v;
  x1h[t] = (f16)v;
}

// one 64-lane wave per row: out[r] = dot(X[r,:], v)
__global__ void k_rowdot(const float* __restrict__ X, const float* __restrict__ v,
                         float* __restrict__ out, int M)
{
  int w = (int)(((long)blockIdx.x * blockDim.x + threadIdx.x) >> 6);
  int lane = threadIdx.x & 63;
  if (w >= M) return;
  float s = 0.f;
  for (int j = lane; j < HID; j += 64) s += X[(size_t)w * HID + j] * v[j];
  for (int o = 32; o; o >>= 1) s += __shfl_down(s, o, 64);
  if (lane == 0) out[w] = s;
}

__global__ void k_rowdot2(const float* __restrict__ X, const float* __restrict__ v1,
                          const float* __restrict__ v2, float* __restrict__ o1,
                          float* __restrict__ o2, int M)
{
  int w = (int)(((long)blockIdx.x * blockDim.x + threadIdx.x) >> 6);
  int lane = threadIdx.x & 63;
  if (w >= M) return;
  float s1 = 0.f, s2 = 0.f;
  for (int j = lane; j < HID; j += 64) {
    float x = X[(size_t)w * HID + j];
    s1 += x * v1[j]; s2 += x * v2[j];
  }
  for (int o = 32; o; o >>= 1) { s1 += __shfl_down(s1, o, 64); s2 += __shfl_down(s2, o, 64); }
  if (lane == 0) { o1[w] = s1; o2[w] = s2; }
}

// GATEConv attention logits, wave per edge; m recomputed on the fly.
__global__ void k_gate_att(const float* __restrict__ P, const float* __restrict__ Te,
                           const int* __restrict__ ei, const int* __restrict__ eai,
                           const float* __restrict__ attl, const float* __restrict__ xr,
                           float* __restrict__ aE, float* __restrict__ mx, int ne)
{
  int e = (int)(((long)blockIdx.x * blockDim.x + threadIdx.x) >> 6);
  int lane = threadIdx.x & 63;
  if (e >= ne) return;
  int s = ei[e];
  int i0 = eai[e * 3], i1 = eai[e * 3 + 1], i2 = eai[e * 3 + 2];
  float acc = 0.f;
  for (int j = lane; j < HID; j += 64) {
    float m = P[(size_t)s * HID + j] + Te[(size_t)i0 * HID + j]
            + Te[(size_t)i1 * HID + j] + Te[(size_t)i2 * HID + j];
    acc += leaky(m) * attl[j];
  }
  for (int o = 32; o; o >>= 1) acc += __shfl_down(acc, o, 64);
  if (lane == 0) {
    int d = ei[NE + e];
    float a = leaky(acc + xr[d]);
    aE[e] = a;
    atomicMaxF(&mx[d], a);
  }
}

__global__ void k_gat_att(const float* __restrict__ sS, const float* __restrict__ sD,
                          const int* __restrict__ ei, float* __restrict__ aE,
                          float* __restrict__ mx, int ne)
{
  int e = (int)((long)blockIdx.x * blockDim.x + threadIdx.x);
  if (e >= ne) return;
  int s = ei[e], d = ei[NE + e];
  float a = leaky(sS[s] + sD[d]);
  aE[e] = a;
  atomicMaxF(&mx[d], a);
}

__global__ void k_mol_att(const float* __restrict__ a_node, const float* __restrict__ a_g,
                          const int* __restrict__ batch, float* __restrict__ aN,
                          float* __restrict__ mxG, int n)
{
  int i = (int)((long)blockIdx.x * blockDim.x + threadIdx.x);
  if (i >= n) return;
  int b = batch[i];
  float a = leaky(a_node[i] + a_g[b]);
  aN[i] = a;
  atomicMaxF(&mxG[b], a);
}

__global__ void k_seg_exp(float* __restrict__ a, const int* __restrict__ idx,
                          const float* __restrict__ mx, float* __restrict__ sum, int n)
{
  int t = (int)((long)blockIdx.x * blockDim.x + threadIdx.x);
  if (t >= n) return;
  int d = idx[t];
  float e = expf(a[t] - mx[d]);
  a[t] = e;
  atomicAdd(&sum[d], e);
}

__global__ void k_scatter_edge(const float* __restrict__ P, const float* __restrict__ Te,
                               const int* __restrict__ ei, const int* __restrict__ eai,
                               const float* __restrict__ aE, const float* __restrict__ sum,
                               float* __restrict__ acc, long total)
{
  long t = (long)blockIdx.x * blockDim.x + threadIdx.x;
  if (t >= total) return;
  int e = (int)(t / HID), c = (int)(t % HID);
  int s = ei[e], d = ei[NE + e];
  float m = P[(size_t)s * HID + c] + Te[(size_t)eai[e * 3] * HID + c]
          + Te[(size_t)eai[e * 3 + 1] * HID + c] + Te[(size_t)eai[e * 3 + 2] * HID + c];
  m = leaky(m);
  float w = aE[e] / (sum[d] + 1e-16f);
  atomicAdd(&acc[(size_t)d * HID + c], m * w);
}

__global__ void k_scatter_gat(const float* __restrict__ XL, const float* __restrict__ aE,
                              const float* __restrict__ sum, const int* __restrict__ ei,
                              float* __restrict__ acc, long total)
{
  long t = (long)blockIdx.x * blockDim.x + threadIdx.x;
  if (t >= total) return;
  int e = (int)(t / HID), c = (int)(t % HID);
  int s = ei[e], d = ei[NE + e];
  float w = aE[e] / (sum[d] + 1e-16f);
  atomicAdd(&acc[(size_t)d * HID + c], XL[(size_t)s * HID + c] * w);
}

__global__ void k_scatter_node(const float* __restrict__ XLm, const float* __restrict__ aN,
                               const float* __restrict__ sumG, const int* __restrict__ batch,
                               float* __restrict__ HM, long total)
{
  long t = (long)blockIdx.x * blockDim.x + threadIdx.x;
  if (t >= total) return;
  int i = (int)(t / HID), c = (int)(t % HID);
  int b = batch[i];
  float w = aN[i] / (sumG[b] + 1e-16f);
  atomicAdd(&HM[(size_t)b * HID + c], XLm[t] * w);
}

__global__ void k_scatter_sum(const float* __restrict__ X, const int* __restrict__ batch,
                              float* __restrict__ acc, long total)
{
  long t = (long)blockIdx.x * blockDim.x + threadIdx.x;
  if (t >= total) return;
  int i = (int)(t / HID), c = (int)(t % HID);
  atomicAdd(&acc[(size_t)batch[i] * HID + c], X[t]);
}

// X[t] = act(X[t] + bias[c]); act: 2=elu 3=relu; optional f16 dual out
__global__ void k_bias_act(float* __restrict__ X, const float* __restrict__ bias,
                           f16* __restrict__ Xh, long total, int act)
{
  long t = (long)blockIdx.x * blockDim.x + threadIdx.x;
  if (t >= total) return;
  int c = (int)(t % HID);
  float v = X[t];
  if (bias) v += bias[c];
  if (act == 2) v = elu1(v);
  else if (act == 3) v = fmaxf(v, 0.f);
  X[t] = v;
  if (Xh) Xh[t] = (f16)v;
}

extern "C" void kernel_launch(void* const* d_in, const int* in_sizes, int n_in,
                              void* d_out, int out_size, void* d_ws, size_t ws_size,
                              hipStream_t stream)
{
  const int* x_idx = (const int*)d_in[0];
  const int* edge_index = (const int*)d_in[1];
  const int* eai = (const int*)d_in[2];
  const int* batch = (const int*)d_in[3];
  const float* x_emb = (const float*)d_in[4];
  const float* e_emb = (const float*)d_in[5];
  const float* lin1_W = (const float*)d_in[6];
  const float* lin1_b = (const float*)d_in[7];
  const float* att_l = (const float*)d_in[8];
  const float* att_r = (const float*)d_in[9];
  const float* gl1_W = (const float*)d_in[10];
  const float* gl2_W = (const float*)d_in[11];
  const float* gate_b = (const float*)d_in[12];
  const float* gru1_Wi = (const float*)d_in[13];
  const float* gru1_Wh = (const float*)d_in[14];
  const float* gru1_bi = (const float*)d_in[15];
  const float* gru1_bh = (const float*)d_in[16];
  const float* gat_W = (const float*)d_in[17];
  const float* gat_as = (const float*)d_in[18];
  const float* gat_ad = (const float*)d_in[19];
  const float* gat_b = (const float*)d_in[20];
  const float* gru2_Wi = (const float*)d_in[21];
  const float* gru2_Wh = (const float*)d_in[22];
  const float* gru2_bi = (const float*)d_in[23];
  const float* gru2_bh = (const float*)d_in[24];
  const float* mol_W = (const float*)d_in[25];
  const float* mol_as = (const float*)d_in[26];
  const float* mol_ad = (const float*)d_in[27];
  const float* mol_b = (const float*)d_in[28];
  const float* mgru_Wi = (const float*)d_in[29];
  const float* mgru_Wh = (const float*)d_in[30];
  const float* mgru_bi = (const float*)d_in[31];
  const float* mgru_bh = (const float*)d_in[32];
  const float* lin2_W = (const float*)d_in[33];
  const float* lin2_b = (const float*)d_in[34];
  float* outp = (float*)d_out;

  const size_t NB = (size_t)NN * HID;
  const size_t GB = (size_t)NG * HID;

  float* ws = (float*)d_ws;
  size_t off = 0;
  auto alloc = [&](size_t n) { float* p = ws + off; off += n; return p; };
  auto alloch = [&](size_t n) { f16* p = (f16*)(ws + off); off += (n + 1) / 2; return p; };
  float* A    = alloc(NB);
  float* B    = alloc(NB);
  float* C    = alloc(NB);
  f16* H1 = alloch(NB);
  f16* H2 = alloch(NB);
  f16* H3 = alloch(NB);
  f16* W1t   = alloch((size_t)HID * HID);        // gl1_W A-part ^T
  f16* W2t   = alloch((size_t)HID * HID);        // gl2_W ^T
  f16* Wgatt = alloch((size_t)HID * HID);
  f16* Wmolt = alloch((size_t)HID * HID);
  f16* Wg1it = alloch((size_t)3 * HID * HID);
  f16* Wg1ht = alloch((size_t)3 * HID * HID);
  f16* Wg2it = alloch((size_t)3 * HID * HID);
  f16* Wg2ht = alloch((size_t)3 * HID * HID);
  float* T1   = alloc((size_t)178 * HID);
  float* Te   = alloc((size_t)18 * HID);
  float* xr   = alloc(NN);
  float* sS   = alloc(NN);
  float* sD   = alloc(NN);
  float* mxN  = alloc(NN);
  float* sumN = alloc(NN);
  float* aN   = alloc(NN);
  float* a_node = alloc(NN);
  float* aE   = alloc(NE);
  float* mxG  = alloc(NG);
  float* sumG = alloc(NG);
  float* a_g  = alloc(NG);
  float* OUTa = alloc(GB);
  float* OUTb = alloc(GB);
  float* GM   = alloc(GB);
  float* HM   = alloc(GB);
  (void)n_in; (void)in_sizes; (void)out_size;
  if (ws_size < off * sizeof(float)) return;  // fail loud, not with a GPU fault

  const int* dstArr = edge_index + NE;
  dim3 blk(256);
  dim3 blkT(32, 8);
  auto g1 = [](long n) { return dim3((unsigned)((n + 255) / 256)); };
  auto gw = [](long waves) { return dim3((unsigned)((waves * 64 + 255) / 256)); };
  const long NBt = (long)NB, EBt = (long)NE * HID, GBt = (long)GB;
  // 1D XCD-grouped grids for the no-LDS MFMA kernels
  const int MtH = (NN + 127) / 128;                       // 235
  const dim3 gH((unsigned)(8 * 3 * ((MtH + 7) / 8)));     // 720
  const int MtR = (NN + 63) / 64;                         // 469
  const dim3 gR((unsigned)(8 * 6 * ((MtR + 7) / 8)));     // 2832
  const dim3 gG(HID / 64, (NG + 63) / 64);                // f32 G-sized grid

  // ---- weight prep: f16 transposed copies ----
  hipLaunchKernelGGL(k_wt_h, dim3(HID / 32, HID / 32), blkT, 0, stream, gl1_W, W1t, HID, HID);
  hipLaunchKernelGGL(k_wt_h, dim3(HID / 32, HID / 32), blkT, 0, stream, gl2_W, W2t, HID, HID);
  hipLaunchKernelGGL(k_wt_h, dim3(HID / 32, HID / 32), blkT, 0, stream, gat_W, Wgatt, HID, HID);
  hipLaunchKernelGGL(k_wt_h, dim3(HID / 32, HID / 32), blkT, 0, stream, mol_W, Wmolt, HID, HID);
  hipLaunchKernelGGL(k_wt_h, dim3(HID / 32, 3 * HID / 32), blkT, 0, stream, gru1_Wi, Wg1it, HID, 3 * HID);
  hipLaunchKernelGGL(k_wt_h, dim3(HID / 32, 3 * HID / 32), blkT, 0, stream, gru1_Wh, Wg1ht, HID, 3 * HID);
  hipLaunchKernelGGL(k_wt_h, dim3(HID / 32, 3 * HID / 32), blkT, 0, stream, gru2_Wi, Wg2it, HID, 3 * HID);
  hipLaunchKernelGGL(k_wt_h, dim3(HID / 32, 3 * HID / 32), blkT, 0, stream, gru2_Wh, Wg2ht, HID, 3 * HID);

  // ---- tables ----
  hipLaunchKernelGGL(k_gemm, dim3(HID / 64, 3), blk, 0, stream,
                     x_emb, lin1_W, nullptr, T1, 178, HID, EMB, 0);
  hipLaunchKernelGGL(k_gemm, dim3(HID / 64, 1), blk, 0, stream,
                     e_emb, gl1_W + (size_t)HID * HID, nullptr, Te, 18, HID, EMB, 0);

  // ---- x1 ----
  hipLaunchKernelGGL(k_node_embed, g1(NBt), blk, 0, stream, x_idx, T1, lin1_b, A, H1, NBt);

  // ---- GATEConv ----
  hipLaunchKernelGGL(k_hgemm, gH, blk, 0, stream, H1, W1t, nullptr, B, (f16*)nullptr, NN, HID, 0); // P
  hipLaunchKernelGGL(k_rowdot, gw(NN), blk, 0, stream, A, att_r, xr, NN);
  hipMemsetAsync(mxN, 0xFF, NN * sizeof(float), stream);
  hipLaunchKernelGGL(k_gate_att, gw(NE), blk, 0, stream, B, Te, edge_index, eai, att_l, xr, aE, mxN, NE);
  hipMemsetAsync(sumN, 0, NN * sizeof(float), stream);
  hipLaunchKernelGGL(k_seg_exp, g1(NE), blk, 0, stream, aE, dstArr, mxN, sumN, NE);
  hipMemsetAsync(C, 0, NB * sizeof(float), stream);
  hipLaunchKernelGGL(k_scatter_edge, g1(EBt), blk, 0, stream, B, Te, edge_index, eai, aE, sumN, C, EBt);
  hipLaunchKernelGGL(k_f2h, g1(NBt), blk, 0, stream, C, H2, NBt);
  hipLaunchKernelGGL(k_hgemm, gH, blk, 0, stream, H2, W2t, gate_b, (float*)nullptr, H3, NN, HID, 2); // elu(h) f16
  // GRU1: x2 -> C (f32) + H2 (f16)
  hipLaunchKernelGGL(k_gru_hgemm, gR, blk, 0, stream, H3, H1, A, Wg1it, Wg1ht, gru1_bi, gru1_bh, C, H2, NN);

  // ---- GAT layer ----
  hipLaunchKernelGGL(k_hgemm, gH, blk, 0, stream, H2, Wgatt, nullptr, B, (f16*)nullptr, NN, HID, 0); // XL
  hipLaunchKernelGGL(k_rowdot2, gw(NN), blk, 0, stream, B, gat_as, gat_ad, sS, sD, NN);
  hipMemsetAsync(mxN, 0xFF, NN * sizeof(float), stream);
  hipLaunchKernelGGL(k_gat_att, g1(NE), blk, 0, stream, sS, sD, edge_index, aE, mxN, NE);
  hipMemsetAsync(sumN, 0, NN * sizeof(float), stream);
  hipLaunchKernelGGL(k_seg_exp, g1(NE), blk, 0, stream, aE, dstArr, mxN, sumN, NE);
  hipMemsetAsync(A, 0, NB * sizeof(float), stream);
  hipLaunchKernelGGL(k_scatter_gat, g1(EBt), blk, 0, stream, B, aE, sumN, edge_index, A, EBt);
  hipLaunchKernelGGL(k_bias_act, g1(NBt), blk, 0, stream, A, gat_b, H1, NBt, 2); // A=elu, H1=f16
  // GRU2: x3 -> B (f32) + H3 (f16)
  hipLaunchKernelGGL(k_gru_hgemm, gR, blk, 0, stream, H1, H2, C, Wg2it, Wg2ht, gru2_bi, gru2_bh, B, H3, NN);

  // ---- molecule readout ----
  hipMemsetAsync(OUTa, 0, GB * sizeof(float), stream);
  hipLaunchKernelGGL(k_scatter_sum, g1(NBt), blk, 0, stream, B, batch, OUTa, NBt);
  hipLaunchKernelGGL(k_bias_act, g1(GBt), blk, 0, stream, OUTa, (const float*)nullptr, (f16*)nullptr, GBt, 3);
  hipLaunchKernelGGL(k_hgemm, gH, blk, 0, stream, H3, Wmolt, nullptr, A, (f16*)nullptr, NN, HID, 0); // XLm
  hipLaunchKernelGGL(k_rowdot, gw(NN), blk, 0, stream, A, mol_as, a_node, NN);

  float* cur = OUTa;
  float* nxt = OUTb;
  for (int t = 0; t < 3; t++) {
    hipLaunchKernelGGL(k_gemm, gG, blk, 0, stream, cur, mol_W, nullptr, GM, NG, HID, HID, 0);
    hipLaunchKernelGGL(k_rowdot, gw(NG), blk, 0, stream, GM, mol_ad, a_g, NG);
    hipMemsetAsync(mxG, 0xFF, NG * sizeof(float), stream);
    hipLaunchKernelGGL(k_mol_att, g1(NN), blk, 0, stream, a_node, a_g, batch, aN, mxG, NN);
    hipMemsetAsync(sumG, 0, NG * sizeof(float), stream);
    hipLaunchKernelGGL(k_seg_exp, g1(NN), blk, 0, stream, aN, batch, mxG, sumG, NN);
    hipMemsetAsync(HM, 0, GB * sizeof(float), stream);
    hipLaunchKernelGGL(k_scatter_node, g1(NBt), blk, 0, stream, A, aN, sumG, batch, HM, NBt);
    hipLaunchKernelGGL(k_bias_act, g1(GBt), blk, 0, stream, HM, mol_b, (f16*)nullptr, GBt, 2);
    hipLaunchKernelGGL(k_gru_gemm, gG, blk, 0, stream, HM, cur, mgru_Wi, mgru_Wh, mgru_bi, mgru_bh, nxt, NG);
    float* tmp = cur; cur = nxt; nxt = tmp;
  }

  // ---- final projection ----
  hipLaunchKernelGGL(k_gemm, dim3(OUTD / 64, (NG + 63) / 64), blk, 0, stream,
                     cur, lin2_W, lin2_b, outp, NG, OUTD, HID, 0);
}

// Round 5
// 1798.114 us; speedup vs baseline: 1.2218x; 1.2218x over previous
//
#include <hip/hip_runtime.h>
#include <cstdint>
#include <cstddef>

#define NN 30000
#define NE 60000
#define NG 1200
#define HID 384
#define EMB 768
#define OUTD 768
#define NEGS 0.01f

typedef _Float16 f16;
typedef _Float16 f16x8 __attribute__((ext_vector_type(8)));
typedef float f32x16 __attribute__((ext_vector_type(16)));

static __device__ __forceinline__ float leaky(float x){ return x > 0.f ? x : NEGS * x; }
static __device__ __forceinline__ float elu1(float x){ return x > 0.f ? x : (expf(x) - 1.f); }
static __device__ __forceinline__ float sigm(float x){ return 1.f / (1.f + expf(-x)); }

static __device__ __forceinline__ void atomicMaxF(float* a, float v){
  if (v >= 0.f) atomicMax((int*)a, __float_as_int(v));
  else atomicMin((unsigned int*)a, __float_as_uint(v));
}

// ---- fragment-packed (PF) layout for K=384 operands of mfma_32x32x16 ----
// chunk(rb,ks,lhi,l31) holds X[rb*32+l31][ks*16+lhi*8 .. +8]; wave reads 1KB contiguous.
// elem index for (row,col): rb=row>>5, l31=row&31, ks=col>>4, lhi=(col>>3)&1, e=col&7
static __device__ __forceinline__ size_t pf_idx(int row, int col){
  return (((((size_t)(row >> 5)) * 24 + (col >> 4)) * 2 + ((col >> 3) & 1)) * 32
          + (row & 31)) * 8 + (col & 7);
}
#define PF_RB_STRIDE 12288   // 24 ks * 64 lanes * 8 elems
#define PF_KS_STRIDE 512     // 64 lanes * 8 elems
#define PF_GATE_STRIDE 147456  // 12 rb * PF_RB_STRIDE  (= HID*HID)

// ---------------- f32 tiled GEMM (small/G-sized ops) ----------------
__global__ __launch_bounds__(256) void k_gemm(
    const float* __restrict__ A, const float* __restrict__ B,
    const float* __restrict__ bias, float* __restrict__ C,
    int M, int N, int K, int act)
{
  __shared__ float As[16][65];
  __shared__ float Bs[16][65];
  const int tid = threadIdx.x;
  const int tx = tid & 15, ty = tid >> 4;
  const int row0 = blockIdx.y * 64, col0 = blockIdx.x * 64;
  const int ar = tid >> 2, ak = (tid & 3) << 2;
  const int bk = tid >> 4, bc = (tid & 15) << 2;
  float acc[4][4] = {};
  for (int k0 = 0; k0 < K; k0 += 16) {
    float4 av = make_float4(0.f, 0.f, 0.f, 0.f);
    if (row0 + ar < M)
      av = *(const float4*)(A + (size_t)(row0 + ar) * K + k0 + ak);
    As[ak + 0][ar] = av.x; As[ak + 1][ar] = av.y;
    As[ak + 2][ar] = av.z; As[ak + 3][ar] = av.w;
    float4 bv = *(const float4*)(B + (size_t)(k0 + bk) * N + col0 + bc);
    Bs[bk][bc + 0] = bv.x; Bs[bk][bc + 1] = bv.y;
    Bs[bk][bc + 2] = bv.z; Bs[bk][bc + 3] = bv.w;
    __syncthreads();
#pragma unroll
    for (int kk = 0; kk < 16; kk++) {
      float a[4], b[4];
#pragma unroll
      for (int i = 0; i < 4; i++) a[i] = As[kk][(ty << 2) + i];
#pragma unroll
      for (int j = 0; j < 4; j++) b[j] = Bs[kk][(tx << 2) + j];
#pragma unroll
      for (int i = 0; i < 4; i++)
#pragma unroll
        for (int j = 0; j < 4; j++)
          acc[i][j] = fmaf(a[i], b[j], acc[i][j]);
    }
    __syncthreads();
  }
#pragma unroll
  for (int i = 0; i < 4; i++) {
    int r = row0 + (ty << 2) + i;
    if (r >= M) continue;
#pragma unroll
    for (int j = 0; j < 4; j++) {
      int c = col0 + (tx << 2) + j;
      float v = acc[i][j];
      if (bias) v += bias[c];
      if (act == 1) v = leaky(v);
      else if (act == 2) v = elu1(v);
      else if (act == 3) v = fmaxf(v, 0.f);
      C[(size_t)r * N + c] = v;
    }
  }
}

// ------------- f32 fused GRU GEMM (G-sized mol loop) -------------
__global__ __launch_bounds__(256) void k_gru_gemm(
    const float* __restrict__ U, const float* __restrict__ Hs,
    const float* __restrict__ Wi, const float* __restrict__ Wh,
    const float* __restrict__ bi, const float* __restrict__ bh,
    float* __restrict__ Xo, int M)
{
  __shared__ float Us[16][65];
  __shared__ float Hss[16][65];
  __shared__ float Bis[3][16][65];
  __shared__ float Bhs[3][16][65];
  const int tid = threadIdx.x;
  const int tx = tid & 15, ty = tid >> 4;
  const int row0 = blockIdx.y * 64, col0 = blockIdx.x * 64;
  const int ar = tid >> 2, ak = (tid & 3) << 2;
  const int bk = tid >> 4, bc = (tid & 15) << 2;
  float aR[4][4] = {}, aZ[4][4] = {}, aN_[4][4] = {};
  float hR[4][4] = {}, hZ[4][4] = {}, hN[4][4] = {};
  for (int k0 = 0; k0 < HID; k0 += 16) {
    float4 uv = make_float4(0.f, 0.f, 0.f, 0.f);
    float4 hv = make_float4(0.f, 0.f, 0.f, 0.f);
    if (row0 + ar < M) {
      uv = *(const float4*)(U  + (size_t)(row0 + ar) * HID + k0 + ak);
      hv = *(const float4*)(Hs + (size_t)(row0 + ar) * HID + k0 + ak);
    }
    Us[ak + 0][ar] = uv.x; Us[ak + 1][ar] = uv.y;
    Us[ak + 2][ar] = uv.z; Us[ak + 3][ar] = uv.w;
    Hss[ak + 0][ar] = hv.x; Hss[ak + 1][ar] = hv.y;
    Hss[ak + 2][ar] = hv.z; Hss[ak + 3][ar] = hv.w;
#pragma unroll
    for (int g = 0; g < 3; g++) {
      float4 bv = *(const float4*)(Wi + (size_t)(k0 + bk) * (3 * HID) + g * HID + col0 + bc);
      Bis[g][bk][bc + 0] = bv.x; Bis[g][bk][bc + 1] = bv.y;
      Bis[g][bk][bc + 2] = bv.z; Bis[g][bk][bc + 3] = bv.w;
      float4 cv = *(const float4*)(Wh + (size_t)(k0 + bk) * (3 * HID) + g * HID + col0 + bc);
      Bhs[g][bk][bc + 0] = cv.x; Bhs[g][bk][bc + 1] = cv.y;
      Bhs[g][bk][bc + 2] = cv.z; Bhs[g][bk][bc + 3] = cv.w;
    }
    __syncthreads();
#pragma unroll
    for (int kk = 0; kk < 16; kk++) {
      float au[4], ah[4];
#pragma unroll
      for (int i = 0; i < 4; i++) { au[i] = Us[kk][(ty << 2) + i]; ah[i] = Hss[kk][(ty << 2) + i]; }
      float br[4], bz[4], bn[4], cr[4], cz[4], cn[4];
#pragma unroll
      for (int j = 0; j < 4; j++) {
        br[j] = Bis[0][kk][(tx << 2) + j]; bz[j] = Bis[1][kk][(tx << 2) + j]; bn[j] = Bis[2][kk][(tx << 2) + j];
        cr[j] = Bhs[0][kk][(tx << 2) + j]; cz[j] = Bhs[1][kk][(tx << 2) + j]; cn[j] = Bhs[2][kk][(tx << 2) + j];
      }
#pragma unroll
      for (int i = 0; i < 4; i++)
#pragma unroll
        for (int j = 0; j < 4; j++) {
          aR[i][j]  = fmaf(au[i], br[j], aR[i][j]);
          aZ[i][j]  = fmaf(au[i], bz[j], aZ[i][j]);
          aN_[i][j] = fmaf(au[i], bn[j], aN_[i][j]);
          hR[i][j]  = fmaf(ah[i], cr[j], hR[i][j]);
          hZ[i][j]  = fmaf(ah[i], cz[j], hZ[i][j]);
          hN[i][j]  = fmaf(ah[i], cn[j], hN[i][j]);
        }
    }
    __syncthreads();
  }
#pragma unroll
  for (int i = 0; i < 4; i++) {
    int r = row0 + (ty << 2) + i;
    if (r >= M) continue;
#pragma unroll
    for (int j = 0; j < 4; j++) {
      int c = col0 + (tx << 2) + j;
      float rg = sigm(aR[i][j] + bi[c] + hR[i][j] + bh[c]);
      float zg = sigm(aZ[i][j] + bi[HID + c] + hZ[i][j] + bh[HID + c]);
      float ng = tanhf(aN_[i][j] + bi[2 * HID + c] + rg * (hN[i][j] + bh[2 * HID + c]));
      float o = (1.f - zg) * ng + zg * Hs[(size_t)r * HID + c];
      Xo[(size_t)r * HID + c] = fmaxf(o, 0.f);
    }
  }
}

// ------------- MFMA f16 GEMM, PF operands, no LDS -------------
// C = act(A[M,384] @ B[Nn,384]^T + bias); A,B in PF layout. 128x128 block, 4 waves 2x2.
__global__ __launch_bounds__(256) void k_hgemm(
    const f16* __restrict__ Apf, const f16* __restrict__ Bpf,
    const float* __restrict__ bias, float* __restrict__ Cf, f16* __restrict__ Ch,
    int M, int Nn, int act)
{
  const int nct = Nn >> 7;
  const int id = blockIdx.x;
  const int lane8 = id & 7, chunk = id >> 3;
  const int ct = chunk % nct, rg = chunk / nct;
  const int rt = rg * 8 + lane8;
  const int Mt = (M + 127) >> 7;
  if (rt >= Mt) return;
  const int r0 = rt * 128, n0 = ct * 128;
  const int tid = threadIdx.x;
  const int wid = tid >> 6, lane = tid & 63;
  const int wr = wid >> 1, wc = wid & 1;
  const int l31 = lane & 31, lhi = lane >> 5;
  const size_t lane_off = (size_t)(lhi * 32 + l31) * 8;
  const f16* pA[2]; const f16* pB[2];
#pragma unroll
  for (int i = 0; i < 2; i++) {
    pA[i] = Apf + (size_t)(r0 / 32 + wr * 2 + i) * PF_RB_STRIDE + lane_off;
    pB[i] = Bpf + (size_t)(n0 / 32 + wc * 2 + i) * PF_RB_STRIDE + lane_off;
  }
  f32x16 acc[2][2];
#pragma unroll
  for (int i = 0; i < 2; i++)
#pragma unroll
    for (int j = 0; j < 2; j++)
#pragma unroll
      for (int r = 0; r < 16; r++) acc[i][j][r] = 0.f;
#pragma unroll 4
  for (int ks = 0; ks < 24; ks++) {
    f16x8 af[2], bf[2];
#pragma unroll
    for (int i = 0; i < 2; i++) af[i] = *(const f16x8*)(pA[i] + (size_t)ks * PF_KS_STRIDE);
#pragma unroll
    for (int j = 0; j < 2; j++) bf[j] = *(const f16x8*)(pB[j] + (size_t)ks * PF_KS_STRIDE);
#pragma unroll
    for (int i = 0; i < 2; i++)
#pragma unroll
      for (int j = 0; j < 2; j++)
        acc[i][j] = __builtin_amdgcn_mfma_f32_32x32x16_f16(af[i], bf[j], acc[i][j], 0, 0, 0);
  }
#pragma unroll
  for (int i = 0; i < 2; i++)
#pragma unroll
    for (int j = 0; j < 2; j++) {
      int col = n0 + wc * 64 + j * 32 + l31;
      float bv = bias ? bias[col] : 0.f;
#pragma unroll
      for (int r = 0; r < 16; r++) {
        int row = r0 + wr * 64 + i * 32 + (r & 3) + 8 * (r >> 2) + 4 * lhi;
        if (row < M) {
          float v = acc[i][j][r] + bv;
          if (act == 1) v = leaky(v);
          else if (act == 2) v = elu1(v);
          else if (act == 3) v = fmaxf(v, 0.f);
          if (Cf) Cf[(size_t)row * Nn + col] = v;
          if (Ch) Ch[pf_idx(row, col)] = (f16)v;  // only used when Nn==HID
        }
      }
    }
}

// ------------- MFMA f16 fused GRU, PF operands, no LDS -------------
// Wip/Whp: PF with rb spanning gates (gate g -> rb 12g..12g+11). 64x64 block, 4 waves 2x2.
__global__ __launch_bounds__(256) void k_gru_hgemm(
    const f16* __restrict__ Upf, const f16* __restrict__ Hpf, const float* __restrict__ Hsf,
    const f16* __restrict__ Wip, const f16* __restrict__ Whp,
    const float* __restrict__ bi, const float* __restrict__ bh,
    float* __restrict__ Xo, f16* __restrict__ Xoh, int M)
{
  const int id = blockIdx.x;
  const int lane8 = id & 7, chunk = id >> 3;
  const int ct = chunk % 6, rg = chunk / 6;
  const int rt = rg * 8 + lane8;
  const int Mt = (M + 63) >> 6;
  if (rt >= Mt) return;
  const int r0 = rt * 64, c0 = ct * 64;
  const int tid = threadIdx.x;
  const int wid = tid >> 6, lane = tid & 63;
  const int wr = wid >> 1, wc = wid & 1;
  const int l31 = lane & 31, lhi = lane >> 5;
  const size_t lane_off = (size_t)(lhi * 32 + l31) * 8;
  const f16* pU  = Upf + (size_t)(r0 / 32 + wr) * PF_RB_STRIDE + lane_off;
  const f16* pH  = Hpf + (size_t)(r0 / 32 + wr) * PF_RB_STRIDE + lane_off;
  const f16* pWi = Wip + (size_t)(c0 / 32 + wc) * PF_RB_STRIDE + lane_off;
  const f16* pWh = Whp + (size_t)(c0 / 32 + wc) * PF_RB_STRIDE + lane_off;
#define Z16 {0,0,0,0,0,0,0,0,0,0,0,0,0,0,0,0}
  f32x16 aR = Z16, aZ = Z16, aN = Z16, hR = Z16, hZ = Z16, hN = Z16;
#pragma unroll 4
  for (int ks = 0; ks < 24; ks++) {
    const size_t off = (size_t)ks * PF_KS_STRIDE;
    f16x8 au  = *(const f16x8*)(pU + off);
    f16x8 ah  = *(const f16x8*)(pH + off);
    f16x8 bir = *(const f16x8*)(pWi + off);
    f16x8 biz = *(const f16x8*)(pWi + PF_GATE_STRIDE + off);
    f16x8 bin = *(const f16x8*)(pWi + 2 * PF_GATE_STRIDE + off);
    f16x8 bhr = *(const f16x8*)(pWh + off);
    f16x8 bhz = *(const f16x8*)(pWh + PF_GATE_STRIDE + off);
    f16x8 bhn = *(const f16x8*)(pWh + 2 * PF_GATE_STRIDE + off);
    aR = __builtin_amdgcn_mfma_f32_32x32x16_f16(au, bir, aR, 0, 0, 0);
    aZ = __builtin_amdgcn_mfma_f32_32x32x16_f16(au, biz, aZ, 0, 0, 0);
    aN = __builtin_amdgcn_mfma_f32_32x32x16_f16(au, bin, aN, 0, 0, 0);
    hR = __builtin_amdgcn_mfma_f32_32x32x16_f16(ah, bhr, hR, 0, 0, 0);
    hZ = __builtin_amdgcn_mfma_f32_32x32x16_f16(ah, bhz, hZ, 0, 0, 0);
    hN = __builtin_amdgcn_mfma_f32_32x32x16_f16(ah, bhn, hN, 0, 0, 0);
  }
  const int col = c0 + wc * 32 + l31;  // in [0, 384)
  const float bir_ = bi[col], biz_ = bi[HID + col], bin_ = bi[2 * HID + col];
  const float bhr_ = bh[col], bhz_ = bh[HID + col], bhn_ = bh[2 * HID + col];
#pragma unroll
  for (int r = 0; r < 16; r++) {
    int row = r0 + wr * 32 + (r & 3) + 8 * (r >> 2) + 4 * lhi;
    if (row < M) {
      float rg_ = sigm(aR[r] + hR[r] + bir_ + bhr_);
      float zg = sigm(aZ[r] + hZ[r] + biz_ + bhz_);
      float ng = tanhf(aN[r] + bin_ + rg_ * (hN[r] + bhn_));
      float o = (1.f - zg) * ng + zg * Hsf[(size_t)row * HID + col];
      o = fmaxf(o, 0.f);
      Xo[(size_t)row * HID + col] = o;
      Xoh[pf_idx(row, col)] = (f16)o;
    }
  }
}

// pack weight W[K][Nn] (f32, row-major) -> PF f16 over rows n (output-col major), K=384
__global__ void k_wpack(const float* __restrict__ W, f16* __restrict__ Wp, int K, int Nn)
{
  long t = (long)blockIdx.x * blockDim.x + threadIdx.x;
  if (t >= (long)K * Nn) return;
  int elem = (int)(t & 7); long c = t >> 3;
  int l31 = (int)(c & 31); long q = c >> 5;
  int lhi = (int)(q & 1); long p = q >> 1;
  int KS = K >> 4;
  int ks = (int)(p % KS); int rb = (int)(p / KS);
  int n = rb * 32 + l31, k = ks * 16 + lhi * 8 + elem;
  Wp[t] = (f16)W[(size_t)k * Nn + n];
}

// elementwise f32 row-major -> f16 PF
__global__ void k_f2h_pf(const float* __restrict__ in, f16* __restrict__ out, long total)
{
  long t = (long)blockIdx.x * blockDim.x + threadIdx.x;
  if (t >= total) return;
  int i = (int)(t / HID), c = (int)(t % HID);
  out[pf_idx(i, c)] = (f16)in[t];
}

// x1[i,c] = leaky(sum_j T1[x_idx[i,j], c] + lin1_b[c]); dual f32 + f16-PF out
__global__ void k_node_embed(const int* __restrict__ xi, const float* __restrict__ T1,
                             const float* __restrict__ b, float* __restrict__ x1,
                             f16* __restrict__ x1h, long total)
{
  long t = (long)blockIdx.x * blockDim.x + threadIdx.x;
  if (t >= total) return;
  int i = (int)(t / HID), c = (int)(t % HID);
  float v = b[c];
#pragma unroll
  for (int j = 0; j < 9; j++) v += T1[(size_t)xi[i * 9 + j] * HID + c];
  v = leaky(v);
  x1[t] = v;
  x1h[pf_idx(i, c)] = (f16)v;
}

// one 64-lane wave per row: out[r] = dot(X[r,:], v)
__global__ void k_rowdot(const float* __restrict__ X, const float* __restrict__ v,
                         float* __restrict__ out, int M)
{
  int w = (int)(((long)blockIdx.x * blockDim.x + threadIdx.x) >> 6);
  int lane = threadIdx.x & 63;
  if (w >= M) return;
  float s = 0.f;
  for (int j = lane; j < HID; j += 64) s += X[(size_t)w * HID + j] * v[j];
  for (int o = 32; o; o >>= 1) s += __shfl_down(s, o, 64);
  if (lane == 0) out[w] = s;
}

__global__ void k_rowdot2(const float* __restrict__ X, const float* __restrict__ v1,
                          const float* __restrict__ v2, float* __restrict__ o1,
                          float* __restrict__ o2, int M)
{
  int w = (int)(((long)blockIdx.x * blockDim.x + threadIdx.x) >> 6);
  int lane = threadIdx.x & 63;
  if (w >= M) return;
  float s1 = 0.f, s2 = 0.f;
  for (int j = lane; j < HID; j += 64) {
    float x = X[(size_t)w * HID + j];
    s1 += x * v1[j]; s2 += x * v2[j];
  }
  for (int o = 32; o; o >>= 1) { s1 += __shfl_down(s1, o, 64); s2 += __shfl_down(s2, o, 64); }
  if (lane == 0) { o1[w] = s1; o2[w] = s2; }
}

// GATEConv attention logits, wave per edge; m recomputed on the fly.
__global__ void k_gate_att(const float* __restrict__ P, const float* __restrict__ Te,
                           const int* __restrict__ ei, const int* __restrict__ eai,
                           const float* __restrict__ attl, const float* __restrict__ xr,
                           float* __restrict__ aE, float* __restrict__ mx, int ne)
{
  int e = (int)(((long)blockIdx.x * blockDim.x + threadIdx.x) >> 6);
  int lane = threadIdx.x & 63;
  if (e >= ne) return;
  int s = ei[e];
  int i0 = eai[e * 3], i1 = eai[e * 3 + 1], i2 = eai[e * 3 + 2];
  float acc = 0.f;
  for (int j = lane; j < HID; j += 64) {
    float m = P[(size_t)s * HID + j] + Te[(size_t)i0 * HID + j]
            + Te[(size_t)i1 * HID + j] + Te[(size_t)i2 * HID + j];
    acc += leaky(m) * attl[j];
  }
  for (int o = 32; o; o >>= 1) acc += __shfl_down(acc, o, 64);
  if (lane == 0) {
    int d = ei[NE + e];
    float a = leaky(acc + xr[d]);
    aE[e] = a;
    atomicMaxF(&mx[d], a);
  }
}

__global__ void k_gat_att(const float* __restrict__ sS, const float* __restrict__ sD,
                          const int* __restrict__ ei, float* __restrict__ aE,
                          float* __restrict__ mx, int ne)
{
  int e = (int)((long)blockIdx.x * blockDim.x + threadIdx.x);
  if (e >= ne) return;
  int s = ei[e], d = ei[NE + e];
  float a = leaky(sS[s] + sD[d]);
  aE[e] = a;
  atomicMaxF(&mx[d], a);
}

__global__ void k_mol_att(const float* __restrict__ a_node, const float* __restrict__ a_g,
                          const int* __restrict__ batch, float* __restrict__ aN,
                          float* __restrict__ mxG, int n)
{
  int i = (int)((long)blockIdx.x * blockDim.x + threadIdx.x);
  if (i >= n) return;
  int b = batch[i];
  float a = leaky(a_node[i] + a_g[b]);
  aN[i] = a;
  atomicMaxF(&mxG[b], a);
}

__global__ void k_seg_exp(float* __restrict__ a, const int* __restrict__ idx,
                          const float* __restrict__ mx, float* __restrict__ sum, int n)
{
  int t = (int)((long)blockIdx.x * blockDim.x + threadIdx.x);
  if (t >= n) return;
  int d = idx[t];
  float e = expf(a[t] - mx[d]);
  a[t] = e;
  atomicAdd(&sum[d], e);
}

__global__ void k_scatter_edge(const float* __restrict__ P, const float* __restrict__ Te,
                               const int* __restrict__ ei, const int* __restrict__ eai,
                               const float* __restrict__ aE, const float* __restrict__ sum,
                               float* __restrict__ acc, long total)
{
  long t = (long)blockIdx.x * blockDim.x + threadIdx.x;
  if (t >= total) return;
  int e = (int)(t / HID), c = (int)(t % HID);
  int s = ei[e], d = ei[NE + e];
  float m = P[(size_t)s * HID + c] + Te[(size_t)eai[e * 3] * HID + c]
          + Te[(size_t)eai[e * 3 + 1] * HID + c] + Te[(size_t)eai[e * 3 + 2] * HID + c];
  m = leaky(m);
  float w = aE[e] / (sum[d] + 1e-16f);
  atomicAdd(&acc[(size_t)d * HID + c], m * w);
}

__global__ void k_scatter_gat(const float* __restrict__ XL, const float* __restrict__ aE,
                              const float* __restrict__ sum, const int* __restrict__ ei,
                              float* __restrict__ acc, long total)
{
  long t = (long)blockIdx.x * blockDim.x + threadIdx.x;
  if (t >= total) return;
  int e = (int)(t / HID), c = (int)(t % HID);
  int s = ei[e], d = ei[NE + e];
  float w = aE[e] / (sum[d] + 1e-16f);
  atomicAdd(&acc[(size_t)d * HID + c], XL[(size_t)s * HID + c] * w);
}

__global__ void k_scatter_node(const float* __restrict__ XLm, const float* __restrict__ aN,
                               const float* __restrict__ sumG, const int* __restrict__ batch,
                               float* __restrict__ HM, long total)
{
  long t = (long)blockIdx.x * blockDim.x + threadIdx.x;
  if (t >= total) return;
  int i = (int)(t / HID), c = (int)(t % HID);
  int b = batch[i];
  float w = aN[i] / (sumG[b] + 1e-16f);
  atomicAdd(&HM[(size_t)b * HID + c], XLm[t] * w);
}

__global__ void k_scatter_sum(const float* __restrict__ X, const int* __restrict__ batch,
                              float* __restrict__ acc, long total)
{
  long t = (long)blockIdx.x * blockDim.x + threadIdx.x;
  if (t >= total) return;
  int i = (int)(t / HID), c = (int)(t % HID);
  atomicAdd(&acc[(size_t)batch[i] * HID + c], X[t]);
}

// X[t] = act(X[t] + bias[c]); act: 2=elu 3=relu; optional f16-PF dual out
__global__ void k_bias_act(float* __restrict__ X, const float* __restrict__ bias,
                           f16* __restrict__ Xh, long total, int act)
{
  long t = (long)blockIdx.x * blockDim.x + threadIdx.x;
  if (t >= total) return;
  int i = (int)(t / HID), c = (int)(t % HID);
  float v = X[t];
  if (bias) v += bias[c];
  if (act == 2) v = elu1(v);
  else if (act == 3) v = fmaxf(v, 0.f);
  X[t] = v;
  if (Xh) Xh[pf_idx(i, c)] = (f16)v;
}

extern "C" void kernel_launch(void* const* d_in, const int* in_sizes, int n_in,
                              void* d_out, int out_size, void* d_ws, size_t ws_size,
                              hipStream_t stream)
{
  const int* x_idx = (const int*)d_in[0];
  const int* edge_index = (const int*)d_in[1];
  const int* eai = (const int*)d_in[2];
  const int* batch = (const int*)d_in[3];
  const float* x_emb = (const float*)d_in[4];
  const float* e_emb = (const float*)d_in[5];
  const float* lin1_W = (const float*)d_in[6];
  const float* lin1_b = (const float*)d_in[7];
  const float* att_l = (const float*)d_in[8];
  const float* att_r = (const float*)d_in[9];
  const float* gl1_W = (const float*)d_in[10];
  const float* gl2_W = (const float*)d_in[11];
  const float* gate_b = (const float*)d_in[12];
  const float* gru1_Wi = (const float*)d_in[13];
  const float* gru1_Wh = (const float*)d_in[14];
  const float* gru1_bi = (const float*)d_in[15];
  const float* gru1_bh = (const float*)d_in[16];
  const float* gat_W = (const float*)d_in[17];
  const float* gat_as = (const float*)d_in[18];
  const float* gat_ad = (const float*)d_in[19];
  const float* gat_b = (const float*)d_in[20];
  const float* gru2_Wi = (const float*)d_in[21];
  const float* gru2_Wh = (const float*)d_in[22];
  const float* gru2_bi = (const float*)d_in[23];
  const float* gru2_bh = (const float*)d_in[24];
  const float* mol_W = (const float*)d_in[25];
  const float* mol_as = (const float*)d_in[26];
  const float* mol_ad = (const float*)d_in[27];
  const float* mol_b = (const float*)d_in[28];
  const float* mgru_Wi = (const float*)d_in[29];
  const float* mgru_Wh = (const float*)d_in[30];
  const float* mgru_bi = (const float*)d_in[31];
  const float* mgru_bh = (const float*)d_in[32];
  const float* lin2_W = (const float*)d_in[33];
  const float* lin2_b = (const float*)d_in[34];
  float* outp = (float*)d_out;

  const size_t NB = (size_t)NN * HID;
  const size_t GB = (size_t)NG * HID;
  // PF activation buffer: pad rows to 940*32 = 30080 (hgemm reads up to row 30079)
  const size_t PFH = (size_t)940 * PF_RB_STRIDE;  // f16 elems

  float* ws = (float*)d_ws;
  size_t off = 0;
  auto alloc = [&](size_t n) { float* p = ws + off; off += n; return p; };
  auto alloch = [&](size_t n) { f16* p = (f16*)(ws + off); off += (n + 1) / 2; return p; };
  float* A    = alloc(NB);
  float* B    = alloc(NB);
  float* C    = alloc(NB);
  f16* H1 = alloch(PFH);
  f16* H2 = alloch(PFH);
  f16* H3 = alloch(PFH);
  f16* W1p   = alloch((size_t)HID * HID);
  f16* W2p   = alloch((size_t)HID * HID);
  f16* Wgatp = alloch((size_t)HID * HID);
  f16* Wmolp = alloch((size_t)HID * HID);
  f16* Wg1ip = alloch((size_t)3 * HID * HID);
  f16* Wg1hp = alloch((size_t)3 * HID * HID);
  f16* Wg2ip = alloch((size_t)3 * HID * HID);
  f16* Wg2hp = alloch((size_t)3 * HID * HID);
  float* T1   = alloc((size_t)178 * HID);
  float* Te   = alloc((size_t)18 * HID);
  float* xr   = alloc(NN);
  float* sS   = alloc(NN);
  float* sD   = alloc(NN);
  float* mxN  = alloc(NN);
  float* sumN = alloc(NN);
  float* aN   = alloc(NN);
  float* a_node = alloc(NN);
  float* aE   = alloc(NE);
  float* mxG  = alloc(NG);
  float* sumG = alloc(NG);
  float* a_g  = alloc(NG);
  float* OUTa = alloc(GB);
  float* OUTb = alloc(GB);
  float* GM   = alloc(GB);
  float* HM   = alloc(GB);
  (void)n_in; (void)in_sizes; (void)out_size;
  if (ws_size < off * sizeof(float)) return;  // fail loud, not with a GPU fault

  const int* dstArr = edge_index + NE;
  dim3 blk(256);
  auto g1 = [](long n) { return dim3((unsigned)((n + 255) / 256)); };
  auto gw = [](long waves) { return dim3((unsigned)((waves * 64 + 255) / 256)); };
  const long NBt = (long)NB, EBt = (long)NE * HID, GBt = (long)GB;
  // 1D XCD-grouped grids for the MFMA kernels
  const int MtH = (NN + 127) / 128;                       // 235
  const dim3 gH((unsigned)(8 * 3 * ((MtH + 7) / 8)));     // 720
  const int MtR = (NN + 63) / 64;                         // 469
  const dim3 gR((unsigned)(8 * 6 * ((MtR + 7) / 8)));     // 2832
  const dim3 gG(HID / 64, (NG + 63) / 64);                // f32 G-sized grid

  // ---- weight prep: f16 PF-packed copies ----
  hipLaunchKernelGGL(k_wpack, g1((long)HID * HID), blk, 0, stream, gl1_W, W1p, HID, HID);
  hipLaunchKernelGGL(k_wpack, g1((long)HID * HID), blk, 0, stream, gl2_W, W2p, HID, HID);
  hipLaunchKernelGGL(k_wpack, g1((long)HID * HID), blk, 0, stream, gat_W, Wgatp, HID, HID);
  hipLaunchKernelGGL(k_wpack, g1((long)HID * HID), blk, 0, stream, mol_W, Wmolp, HID, HID);
  hipLaunchKernelGGL(k_wpack, g1((long)3 * HID * HID), blk, 0, stream, gru1_Wi, Wg1ip, HID, 3 * HID);
  hipLaunchKernelGGL(k_wpack, g1((long)3 * HID * HID), blk, 0, stream, gru1_Wh, Wg1hp, HID, 3 * HID);
  hipLaunchKernelGGL(k_wpack, g1((long)3 * HID * HID), blk, 0, stream, gru2_Wi, Wg2ip, HID, 3 * HID);
  hipLaunchKernelGGL(k_wpack, g1((long)3 * HID * HID), blk, 0, stream, gru2_Wh, Wg2hp, HID, 3 * HID);

  // ---- tables ----
  hipLaunchKernelGGL(k_gemm, dim3(HID / 64, 3), blk, 0, stream,
                     x_emb, lin1_W, nullptr, T1, 178, HID, EMB, 0);
  hipLaunchKernelGGL(k_gemm, dim3(HID / 64, 1), blk, 0, stream,
                     e_emb, gl1_W + (size_t)HID * HID, nullptr, Te, 18, HID, EMB, 0);

  // ---- x1 ----
  hipLaunchKernelGGL(k_node_embed, g1(NBt), blk, 0, stream, x_idx, T1, lin1_b, A, H1, NBt);

  // ---- GATEConv ----
  hipLaunchKernelGGL(k_hgemm, gH, blk, 0, stream, H1, W1p, nullptr, B, (f16*)nullptr, NN, HID, 0); // P
  hipLaunchKernelGGL(k_rowdot, gw(NN), blk, 0, stream, A, att_r, xr, NN);
  hipMemsetAsync(mxN, 0xFF, NN * sizeof(float), stream);
  hipLaunchKernelGGL(k_gate_att, gw(NE), blk, 0, stream, B, Te, edge_index, eai, att_l, xr, aE, mxN, NE);
  hipMemsetAsync(sumN, 0, NN * sizeof(float), stream);
  hipLaunchKernelGGL(k_seg_exp, g1(NE), blk, 0, stream, aE, dstArr, mxN, sumN, NE);
  hipMemsetAsync(C, 0, NB * sizeof(float), stream);
  hipLaunchKernelGGL(k_scatter_edge, g1(EBt), blk, 0, stream, B, Te, edge_index, eai, aE, sumN, C, EBt);
  hipLaunchKernelGGL(k_f2h_pf, g1(NBt), blk, 0, stream, C, H2, NBt);
  hipLaunchKernelGGL(k_hgemm, gH, blk, 0, stream, H2, W2p, gate_b, (float*)nullptr, H3, NN, HID, 2); // elu(h)
  // GRU1: x2 -> C (f32) + H2 (f16 PF)
  hipLaunchKernelGGL(k_gru_hgemm, gR, blk, 0, stream, H3, H1, A, Wg1ip, Wg1hp, gru1_bi, gru1_bh, C, H2, NN);

  // ---- GAT layer ----
  hipLaunchKernelGGL(k_hgemm, gH, blk, 0, stream, H2, Wgatp, nullptr, B, (f16*)nullptr, NN, HID, 0); // XL
  hipLaunchKernelGGL(k_rowdot2, gw(NN), blk, 0, stream, B, gat_as, gat_ad, sS, sD, NN);
  hipMemsetAsync(mxN, 0xFF, NN * sizeof(float), stream);
  hipLaunchKernelGGL(k_gat_att, g1(NE), blk, 0, stream, sS, sD, edge_index, aE, mxN, NE);
  hipMemsetAsync(sumN, 0, NN * sizeof(float), stream);
  hipLaunchKernelGGL(k_seg_exp, g1(NE), blk, 0, stream, aE, dstArr, mxN, sumN, NE);
  hipMemsetAsync(A, 0, NB * sizeof(float), stream);
  hipLaunchKernelGGL(k_scatter_gat, g1(EBt), blk, 0, stream, B, aE, sumN, edge_index, A, EBt);
  hipLaunchKernelGGL(k_bias_act, g1(NBt), blk, 0, stream, A, gat_b, H1, NBt, 2); // A=elu, H1=PF
  // GRU2: x3 -> B (f32) + H3 (f16 PF)
  hipLaunchKernelGGL(k_gru_hgemm, gR, blk, 0, stream, H1, H2, C, Wg2ip, Wg2hp, gru2_bi, gru2_bh, B, H3, NN);

  // ---- molecule readout ----
  hipMemsetAsync(OUTa, 0, GB * sizeof(float), stream);
  hipLaunchKernelGGL(k_scatter_sum, g1(NBt), blk, 0, stream, B, batch, OUTa, NBt);
  hipLaunchKernelGGL(k_bias_act, g1(GBt), blk, 0, stream, OUTa, (const float*)nullptr, (f16*)nullptr, GBt, 3);
  hipLaunchKernelGGL(k_hgemm, gH, blk, 0, stream, H3, Wmolp, nullptr, A, (f16*)nullptr, NN, HID, 0); // XLm
  hipLaunchKernelGGL(k_rowdot, gw(NN), blk, 0, stream, A, mol_as, a_node, NN);

  float* cur = OUTa;
  float* nxt = OUTb;
  for (int t = 0; t < 3; t++) {
    hipLaunchKernelGGL(k_gemm, gG, blk, 0, stream, cur, mol_W, nullptr, GM, NG, HID, HID, 0);
    hipLaunchKernelGGL(k_rowdot, gw(NG), blk, 0, stream, GM, mol_ad, a_g, NG);
    hipMemsetAsync(mxG, 0xFF, NG * sizeof(float), stream);
    hipLaunchKernelGGL(k_mol_att, g1(NN), blk, 0, stream, a_node, a_g, batch, aN, mxG, NN);
    hipMemsetAsync(sumG, 0, NG * sizeof(float), stream);
    hipLaunchKernelGGL(k_seg_exp, g1(NN), blk, 0, stream, aN, batch, mxG, sumG, NN);
    hipMemsetAsync(HM, 0, GB * sizeof(float), stream);
    hipLaunchKernelGGL(k_scatter_node, g1(NBt), blk, 0, stream, A, aN, sumG, batch, HM, NBt);
    hipLaunchKernelGGL(k_bias_act, g1(GBt), blk, 0, stream, HM, mol_b, (f16*)nullptr, GBt, 2);
    hipLaunchKernelGGL(k_gru_gemm, gG, blk, 0, stream, HM, cur, mgru_Wi, mgru_Wh, mgru_bi, mgru_bh, nxt, NG);
    float* tmp = cur; cur = nxt; nxt = tmp;
  }

  // ---- final projection ----
  hipLaunchKernelGGL(k_gemm, dim3(OUTD / 64, (NG + 63) / 64), blk, 0, stream,
                     cur, lin2_W, lin2_b, outp, NG, OUTD, HID, 0);
}

// Round 6
// 1297.568 us; speedup vs baseline: 1.6931x; 1.3858x over previous
//
#include <hip/hip_runtime.h>
#include <cstdint>
#include <cstddef>

#define NN 30000
#define NE 60000
#define NG 1200
#define HID 384
#define EMB 768
#define OUTD 768
#define NEGS 0.01f

typedef _Float16 f16;
typedef _Float16 f16x8 __attribute__((ext_vector_type(8)));
typedef float f32x16 __attribute__((ext_vector_type(16)));

static __device__ __forceinline__ float leaky(float x){ return x > 0.f ? x : NEGS * x; }
static __device__ __forceinline__ float elu1(float x){ return x > 0.f ? x : (expf(x) - 1.f); }
static __device__ __forceinline__ float sigm(float x){ return 1.f / (1.f + expf(-x)); }

static __device__ __forceinline__ void atomicMaxF(float* a, float v){
  if (v >= 0.f) atomicMax((int*)a, __float_as_int(v));
  else atomicMin((unsigned int*)a, __float_as_uint(v));
}

// ---- fragment-packed (PF) layout for K=384 operands of mfma_32x32x16 ----
// chunk(rb,ks,lhi,l31) holds X[rb*32+l31][ks*16+lhi*8 .. +8]; wave reads 1KB contiguous.
static __device__ __forceinline__ size_t pf_idx(int row, int col){
  return (((((size_t)(row >> 5)) * 24 + (col >> 4)) * 2 + ((col >> 3) & 1)) * 32
          + (row & 31)) * 8 + (col & 7);
}
#define PF_RB_STRIDE 12288   // 24 ks * 64 lanes * 8 elems
#define PF_KS_STRIDE 512     // 64 lanes * 8 elems
#define PF_GATE_STRIDE 147456  // 12 rb * PF_RB_STRIDE  (= HID*HID)

// ---------------- f32 tiled GEMM (tables only) ----------------
__global__ __launch_bounds__(256) void k_gemm(
    const float* __restrict__ A, const float* __restrict__ B,
    const float* __restrict__ bias, float* __restrict__ C,
    int M, int N, int K, int act)
{
  __shared__ float As[16][65];
  __shared__ float Bs[16][65];
  const int tid = threadIdx.x;
  const int tx = tid & 15, ty = tid >> 4;
  const int row0 = blockIdx.y * 64, col0 = blockIdx.x * 64;
  const int ar = tid >> 2, ak = (tid & 3) << 2;
  const int bk = tid >> 4, bc = (tid & 15) << 2;
  float acc[4][4] = {};
  for (int k0 = 0; k0 < K; k0 += 16) {
    float4 av = make_float4(0.f, 0.f, 0.f, 0.f);
    if (row0 + ar < M)
      av = *(const float4*)(A + (size_t)(row0 + ar) * K + k0 + ak);
    As[ak + 0][ar] = av.x; As[ak + 1][ar] = av.y;
    As[ak + 2][ar] = av.z; As[ak + 3][ar] = av.w;
    float4 bv = *(const float4*)(B + (size_t)(k0 + bk) * N + col0 + bc);
    Bs[bk][bc + 0] = bv.x; Bs[bk][bc + 1] = bv.y;
    Bs[bk][bc + 2] = bv.z; Bs[bk][bc + 3] = bv.w;
    __syncthreads();
#pragma unroll
    for (int kk = 0; kk < 16; kk++) {
      float a[4], b[4];
#pragma unroll
      for (int i = 0; i < 4; i++) a[i] = As[kk][(ty << 2) + i];
#pragma unroll
      for (int j = 0; j < 4; j++) b[j] = Bs[kk][(tx << 2) + j];
#pragma unroll
      for (int i = 0; i < 4; i++)
#pragma unroll
        for (int j = 0; j < 4; j++)
          acc[i][j] = fmaf(a[i], b[j], acc[i][j]);
    }
    __syncthreads();
  }
#pragma unroll
  for (int i = 0; i < 4; i++) {
    int r = row0 + (ty << 2) + i;
    if (r >= M) continue;
#pragma unroll
    for (int j = 0; j < 4; j++) {
      int c = col0 + (tx << 2) + j;
      float v = acc[i][j];
      if (bias) v += bias[c];
      if (act == 1) v = leaky(v);
      else if (act == 2) v = elu1(v);
      else if (act == 3) v = fmaxf(v, 0.f);
      C[(size_t)r * N + c] = v;
    }
  }
}

// ------------- MFMA f16 GEMM, PF operands, no LDS -------------
// C = act(A[M,384] @ B[Nn,384]^T + bias); A,B in PF layout. 128x128 block, 4 waves 2x2.
__global__ __launch_bounds__(256) void k_hgemm(
    const f16* __restrict__ Apf, const f16* __restrict__ Bpf,
    const float* __restrict__ bias, float* __restrict__ Cf, f16* __restrict__ Ch,
    int M, int Nn, int act)
{
  const int nct = Nn >> 7;
  const int id = blockIdx.x;
  const int lane8 = id & 7, chunk = id >> 3;
  const int ct = chunk % nct, rg = chunk / nct;
  const int rt = rg * 8 + lane8;
  const int Mt = (M + 127) >> 7;
  if (rt >= Mt) return;
  const int r0 = rt * 128, n0 = ct * 128;
  const int tid = threadIdx.x;
  const int wid = tid >> 6, lane = tid & 63;
  const int wr = wid >> 1, wc = wid & 1;
  const int l31 = lane & 31, lhi = lane >> 5;
  const size_t lane_off = (size_t)(lhi * 32 + l31) * 8;
  const f16* pA[2]; const f16* pB[2];
#pragma unroll
  for (int i = 0; i < 2; i++) {
    pA[i] = Apf + (size_t)(r0 / 32 + wr * 2 + i) * PF_RB_STRIDE + lane_off;
    pB[i] = Bpf + (size_t)(n0 / 32 + wc * 2 + i) * PF_RB_STRIDE + lane_off;
  }
  f32x16 acc[2][2];
#pragma unroll
  for (int i = 0; i < 2; i++)
#pragma unroll
    for (int j = 0; j < 2; j++)
#pragma unroll
      for (int r = 0; r < 16; r++) acc[i][j][r] = 0.f;
#pragma unroll 4
  for (int ks = 0; ks < 24; ks++) {
    f16x8 af[2], bf[2];
#pragma unroll
    for (int i = 0; i < 2; i++) af[i] = *(const f16x8*)(pA[i] + (size_t)ks * PF_KS_STRIDE);
#pragma unroll
    for (int j = 0; j < 2; j++) bf[j] = *(const f16x8*)(pB[j] + (size_t)ks * PF_KS_STRIDE);
#pragma unroll
    for (int i = 0; i < 2; i++)
#pragma unroll
      for (int j = 0; j < 2; j++)
        acc[i][j] = __builtin_amdgcn_mfma_f32_32x32x16_f16(af[i], bf[j], acc[i][j], 0, 0, 0);
  }
#pragma unroll
  for (int i = 0; i < 2; i++)
#pragma unroll
    for (int j = 0; j < 2; j++) {
      int col = n0 + wc * 64 + j * 32 + l31;
      float bv = bias ? bias[col] : 0.f;
#pragma unroll
      for (int r = 0; r < 16; r++) {
        int row = r0 + wr * 64 + i * 32 + (r & 3) + 8 * (r >> 2) + 4 * lhi;
        if (row < M) {
          float v = acc[i][j][r] + bv;
          if (act == 1) v = leaky(v);
          else if (act == 2) v = elu1(v);
          else if (act == 3) v = fmaxf(v, 0.f);
          if (Cf) Cf[(size_t)row * Nn + col] = v;
          if (Ch) Ch[pf_idx(row, col)] = (f16)v;  // only used when Nn==HID
        }
      }
    }
}

// ------------- MFMA f16 fused GRU, PF operands, no LDS -------------
// Wip/Whp: PF with rb spanning gates (gate g -> rb 12g..12g+11). 64x64 block, 4 waves 2x2.
__global__ __launch_bounds__(256) void k_gru_hgemm(
    const f16* __restrict__ Upf, const f16* __restrict__ Hpf, const float* __restrict__ Hsf,
    const f16* __restrict__ Wip, const f16* __restrict__ Whp,
    const float* __restrict__ bi, const float* __restrict__ bh,
    float* __restrict__ Xo, f16* __restrict__ Xoh, int M)
{
  const int id = blockIdx.x;
  const int lane8 = id & 7, chunk = id >> 3;
  const int ct = chunk % 6, rg = chunk / 6;
  const int rt = rg * 8 + lane8;
  const int Mt = (M + 63) >> 6;
  if (rt >= Mt) return;
  const int r0 = rt * 64, c0 = ct * 64;
  const int tid = threadIdx.x;
  const int wid = tid >> 6, lane = tid & 63;
  const int wr = wid >> 1, wc = wid & 1;
  const int l31 = lane & 31, lhi = lane >> 5;
  const size_t lane_off = (size_t)(lhi * 32 + l31) * 8;
  const f16* pU  = Upf + (size_t)(r0 / 32 + wr) * PF_RB_STRIDE + lane_off;
  const f16* pH  = Hpf + (size_t)(r0 / 32 + wr) * PF_RB_STRIDE + lane_off;
  const f16* pWi = Wip + (size_t)(c0 / 32 + wc) * PF_RB_STRIDE + lane_off;
  const f16* pWh = Whp + (size_t)(c0 / 32 + wc) * PF_RB_STRIDE + lane_off;
#define Z16 {0,0,0,0,0,0,0,0,0,0,0,0,0,0,0,0}
  f32x16 aR = Z16, aZ = Z16, aN = Z16, hR = Z16, hZ = Z16, hN = Z16;
#pragma unroll 4
  for (int ks = 0; ks < 24; ks++) {
    const size_t off = (size_t)ks * PF_KS_STRIDE;
    f16x8 au  = *(const f16x8*)(pU + off);
    f16x8 ah  = *(const f16x8*)(pH + off);
    f16x8 bir = *(const f16x8*)(pWi + off);
    f16x8 biz = *(const f16x8*)(pWi + PF_GATE_STRIDE + off);
    f16x8 bin = *(const f16x8*)(pWi + 2 * PF_GATE_STRIDE + off);
    f16x8 bhr = *(const f16x8*)(pWh + off);
    f16x8 bhz = *(const f16x8*)(pWh + PF_GATE_STRIDE + off);
    f16x8 bhn = *(const f16x8*)(pWh + 2 * PF_GATE_STRIDE + off);
    aR = __builtin_amdgcn_mfma_f32_32x32x16_f16(au, bir, aR, 0, 0, 0);
    aZ = __builtin_amdgcn_mfma_f32_32x32x16_f16(au, biz, aZ, 0, 0, 0);
    aN = __builtin_amdgcn_mfma_f32_32x32x16_f16(au, bin, aN, 0, 0, 0);
    hR = __builtin_amdgcn_mfma_f32_32x32x16_f16(ah, bhr, hR, 0, 0, 0);
    hZ = __builtin_amdgcn_mfma_f32_32x32x16_f16(ah, bhz, hZ, 0, 0, 0);
    hN = __builtin_amdgcn_mfma_f32_32x32x16_f16(ah, bhn, hN, 0, 0, 0);
  }
  const int col = c0 + wc * 32 + l31;  // in [0, 384)
  const float bir_ = bi[col], biz_ = bi[HID + col], bin_ = bi[2 * HID + col];
  const float bhr_ = bh[col], bhz_ = bh[HID + col], bhn_ = bh[2 * HID + col];
#pragma unroll
  for (int r = 0; r < 16; r++) {
    int row = r0 + wr * 32 + (r & 3) + 8 * (r >> 2) + 4 * lhi;
    if (row < M) {
      float rg_ = sigm(aR[r] + hR[r] + bir_ + bhr_);
      float zg = sigm(aZ[r] + hZ[r] + biz_ + bhz_);
      float ng = tanhf(aN[r] + bin_ + rg_ * (hN[r] + bhn_));
      float o = (1.f - zg) * ng + zg * Hsf[(size_t)row * HID + col];
      o = fmaxf(o, 0.f);
      Xo[(size_t)row * HID + col] = o;
      Xoh[pf_idx(row, col)] = (f16)o;
    }
  }
}

// pack weight W[K][Nn] (f32, row-major) -> PF f16 over rows n (output-col major), K=384
__global__ void k_wpack(const float* __restrict__ W, f16* __restrict__ Wp, int K, int Nn)
{
  long t = (long)blockIdx.x * blockDim.x + threadIdx.x;
  if (t >= (long)K * Nn) return;
  int elem = (int)(t & 7); long c = t >> 3;
  int l31 = (int)(c & 31); long q = c >> 5;
  int lhi = (int)(q & 1); long p = q >> 1;
  int KS = K >> 4;
  int ks = (int)(p % KS); int rb = (int)(p / KS);
  int n = rb * 32 + l31, k = ks * 16 + lhi * 8 + elem;
  Wp[t] = (f16)W[(size_t)k * Nn + n];
}

// elementwise f32 row-major -> f16 PF
__global__ void k_f2h_pf(const float* __restrict__ in, f16* __restrict__ out, long total)
{
  long t = (long)blockIdx.x * blockDim.x + threadIdx.x;
  if (t >= total) return;
  int i = (int)(t / HID), c = (int)(t % HID);
  out[pf_idx(i, c)] = (f16)in[t];
}

// x1[i,c] = leaky(sum_j T1[x_idx[i,j], c] + lin1_b[c]); dual f32 + f16-PF out
__global__ void k_node_embed(const int* __restrict__ xi, const float* __restrict__ T1,
                             const float* __restrict__ b, float* __restrict__ x1,
                             f16* __restrict__ x1h, long total)
{
  long t = (long)blockIdx.x * blockDim.x + threadIdx.x;
  if (t >= total) return;
  int i = (int)(t / HID), c = (int)(t % HID);
  float v = b[c];
#pragma unroll
  for (int j = 0; j < 9; j++) v += T1[(size_t)xi[i * 9 + j] * HID + c];
  v = leaky(v);
  x1[t] = v;
  x1h[pf_idx(i, c)] = (f16)v;
}

// one 64-lane wave per row: out[r] = dot(X[r,:], v)
__global__ void k_rowdot(const float* __restrict__ X, const float* __restrict__ v,
                         float* __restrict__ out, int M)
{
  int w = (int)(((long)blockIdx.x * blockDim.x + threadIdx.x) >> 6);
  int lane = threadIdx.x & 63;
  if (w >= M) return;
  float s = 0.f;
  for (int j = lane; j < HID; j += 64) s += X[(size_t)w * HID + j] * v[j];
  for (int o = 32; o; o >>= 1) s += __shfl_down(s, o, 64);
  if (lane == 0) out[w] = s;
}

__global__ void k_rowdot2(const float* __restrict__ X, const float* __restrict__ v1,
                          const float* __restrict__ v2, float* __restrict__ o1,
                          float* __restrict__ o2, int M)
{
  int w = (int)(((long)blockIdx.x * blockDim.x + threadIdx.x) >> 6);
  int lane = threadIdx.x & 63;
  if (w >= M) return;
  float s1 = 0.f, s2 = 0.f;
  for (int j = lane; j < HID; j += 64) {
    float x = X[(size_t)w * HID + j];
    s1 += x * v1[j]; s2 += x * v2[j];
  }
  for (int o = 32; o; o >>= 1) { s1 += __shfl_down(s1, o, 64); s2 += __shfl_down(s2, o, 64); }
  if (lane == 0) { o1[w] = s1; o2[w] = s2; }
}

// GATEConv attention logits, wave per edge; m recomputed on the fly.
__global__ void k_gate_att(const float* __restrict__ P, const float* __restrict__ Te,
                           const int* __restrict__ ei, const int* __restrict__ eai,
                           const float* __restrict__ attl, const float* __restrict__ xr,
                           float* __restrict__ aE, float* __restrict__ mx, int ne)
{
  int e = (int)(((long)blockIdx.x * blockDim.x + threadIdx.x) >> 6);
  int lane = threadIdx.x & 63;
  if (e >= ne) return;
  int s = ei[e];
  int i0 = eai[e * 3], i1 = eai[e * 3 + 1], i2 = eai[e * 3 + 2];
  float acc = 0.f;
  for (int j = lane; j < HID; j += 64) {
    float m = P[(size_t)s * HID + j] + Te[(size_t)i0 * HID + j]
            + Te[(size_t)i1 * HID + j] + Te[(size_t)i2 * HID + j];
    acc += leaky(m) * attl[j];
  }
  for (int o = 32; o; o >>= 1) acc += __shfl_down(acc, o, 64);
  if (lane == 0) {
    int d = ei[NE + e];
    float a = leaky(acc + xr[d]);
    aE[e] = a;
    atomicMaxF(&mx[d], a);
  }
}

__global__ void k_gat_att(const float* __restrict__ sS, const float* __restrict__ sD,
                          const int* __restrict__ ei, float* __restrict__ aE,
                          float* __restrict__ mx, int ne)
{
  int e = (int)((long)blockIdx.x * blockDim.x + threadIdx.x);
  if (e >= ne) return;
  int s = ei[e], d = ei[NE + e];
  float a = leaky(sS[s] + sD[d]);
  aE[e] = a;
  atomicMaxF(&mx[d], a);
}

__global__ void k_mol_att(const float* __restrict__ a_node, const float* __restrict__ a_g,
                          const int* __restrict__ batch, float* __restrict__ aN,
                          float* __restrict__ mxG, int n)
{
  int i = (int)((long)blockIdx.x * blockDim.x + threadIdx.x);
  if (i >= n) return;
  int b = batch[i];
  float a = leaky(a_node[i] + a_g[b]);
  aN[i] = a;
  atomicMaxF(&mxG[b], a);
}

__global__ void k_seg_exp(float* __restrict__ a, const int* __restrict__ idx,
                          const float* __restrict__ mx, float* __restrict__ sum, int n)
{
  int t = (int)((long)blockIdx.x * blockDim.x + threadIdx.x);
  if (t >= n) return;
  int d = idx[t];
  float e = expf(a[t] - mx[d]);
  a[t] = e;
  atomicAdd(&sum[d], e);
}

__global__ void k_scatter_edge(const float* __restrict__ P, const float* __restrict__ Te,
                               const int* __restrict__ ei, const int* __restrict__ eai,
                               const float* __restrict__ aE, const float* __restrict__ sum,
                               float* __restrict__ acc, long total)
{
  long t = (long)blockIdx.x * blockDim.x + threadIdx.x;
  if (t >= total) return;
  int e = (int)(t / HID), c = (int)(t % HID);
  int s = ei[e], d = ei[NE + e];
  float m = P[(size_t)s * HID + c] + Te[(size_t)eai[e * 3] * HID + c]
          + Te[(size_t)eai[e * 3 + 1] * HID + c] + Te[(size_t)eai[e * 3 + 2] * HID + c];
  m = leaky(m);
  float w = aE[e] / (sum[d] + 1e-16f);
  atomicAdd(&acc[(size_t)d * HID + c], m * w);
}

__global__ void k_scatter_gat(const float* __restrict__ XL, const float* __restrict__ aE,
                              const float* __restrict__ sum, const int* __restrict__ ei,
                              float* __restrict__ acc, long total)
{
  long t = (long)blockIdx.x * blockDim.x + threadIdx.x;
  if (t >= total) return;
  int e = (int)(t / HID), c = (int)(t % HID);
  int s = ei[e], d = ei[NE + e];
  float w = aE[e] / (sum[d] + 1e-16f);
  atomicAdd(&acc[(size_t)d * HID + c], XL[(size_t)s * HID + c] * w);
}

__global__ void k_scatter_node(const float* __restrict__ XLm, const float* __restrict__ aN,
                               const float* __restrict__ sumG, const int* __restrict__ batch,
                               float* __restrict__ HM, long total)
{
  long t = (long)blockIdx.x * blockDim.x + threadIdx.x;
  if (t >= total) return;
  int i = (int)(t / HID), c = (int)(t % HID);
  int b = batch[i];
  float w = aN[i] / (sumG[b] + 1e-16f);
  atomicAdd(&HM[(size_t)b * HID + c], XLm[t] * w);
}

__global__ void k_scatter_sum(const float* __restrict__ X, const int* __restrict__ batch,
                              float* __restrict__ acc, long total)
{
  long t = (long)blockIdx.x * blockDim.x + threadIdx.x;
  if (t >= total) return;
  int i = (int)(t / HID), c = (int)(t % HID);
  atomicAdd(&acc[(size_t)batch[i] * HID + c], X[t]);
}

// X[t] = act(X[t] + bias[c]); act: 2=elu 3=relu; optional f16-PF dual out
__global__ void k_bias_act(float* __restrict__ X, const float* __restrict__ bias,
                           f16* __restrict__ Xh, long total, int act)
{
  long t = (long)blockIdx.x * blockDim.x + threadIdx.x;
  if (t >= total) return;
  int i = (int)(t / HID), c = (int)(t % HID);
  float v = X[t];
  if (bias) v += bias[c];
  if (act == 2) v = elu1(v);
  else if (act == 3) v = fmaxf(v, 0.f);
  X[t] = v;
  if (Xh) Xh[pf_idx(i, c)] = (f16)v;
}

extern "C" void kernel_launch(void* const* d_in, const int* in_sizes, int n_in,
                              void* d_out, int out_size, void* d_ws, size_t ws_size,
                              hipStream_t stream)
{
  const int* x_idx = (const int*)d_in[0];
  const int* edge_index = (const int*)d_in[1];
  const int* eai = (const int*)d_in[2];
  const int* batch = (const int*)d_in[3];
  const float* x_emb = (const float*)d_in[4];
  const float* e_emb = (const float*)d_in[5];
  const float* lin1_W = (const float*)d_in[6];
  const float* lin1_b = (const float*)d_in[7];
  const float* att_l = (const float*)d_in[8];
  const float* att_r = (const float*)d_in[9];
  const float* gl1_W = (const float*)d_in[10];
  const float* gl2_W = (const float*)d_in[11];
  const float* gate_b = (const float*)d_in[12];
  const float* gru1_Wi = (const float*)d_in[13];
  const float* gru1_Wh = (const float*)d_in[14];
  const float* gru1_bi = (const float*)d_in[15];
  const float* gru1_bh = (const float*)d_in[16];
  const float* gat_W = (const float*)d_in[17];
  const float* gat_as = (const float*)d_in[18];
  const float* gat_ad = (const float*)d_in[19];
  const float* gat_b = (const float*)d_in[20];
  const float* gru2_Wi = (const float*)d_in[21];
  const float* gru2_Wh = (const float*)d_in[22];
  const float* gru2_bi = (const float*)d_in[23];
  const float* gru2_bh = (const float*)d_in[24];
  const float* mol_W = (const float*)d_in[25];
  const float* mol_as = (const float*)d_in[26];
  const float* mol_ad = (const float*)d_in[27];
  const float* mol_b = (const float*)d_in[28];
  const float* mgru_Wi = (const float*)d_in[29];
  const float* mgru_Wh = (const float*)d_in[30];
  const float* mgru_bi = (const float*)d_in[31];
  const float* mgru_bh = (const float*)d_in[32];
  const float* lin2_W = (const float*)d_in[33];
  const float* lin2_b = (const float*)d_in[34];
  float* outp = (float*)d_out;

  const size_t NB = (size_t)NN * HID;
  const size_t GB = (size_t)NG * HID;
  // PF buffers: N rows pad to 940*32=30080; G rows pad to 40*32=1280 (hgemm reads 128-row tiles)
  const size_t PFH = (size_t)940 * PF_RB_STRIDE;  // f16 elems
  const size_t PFG = (size_t)40 * PF_RB_STRIDE;

  float* ws = (float*)d_ws;
  size_t off = 0;
  auto alloc = [&](size_t n) { float* p = ws + off; off += n; return p; };
  auto alloch = [&](size_t n) { f16* p = (f16*)(ws + off); off += (n + 1) / 2; return p; };
  float* A    = alloc(NB);
  float* B    = alloc(NB);
  float* C    = alloc(NB);
  f16* H1 = alloch(PFH);
  f16* H2 = alloch(PFH);
  f16* H3 = alloch(PFH);
  f16* W1p   = alloch((size_t)HID * HID);
  f16* W2p   = alloch((size_t)HID * HID);
  f16* Wgatp = alloch((size_t)HID * HID);
  f16* Wmolp = alloch((size_t)HID * HID);
  f16* Wg1ip = alloch((size_t)3 * HID * HID);
  f16* Wg1hp = alloch((size_t)3 * HID * HID);
  f16* Wg2ip = alloch((size_t)3 * HID * HID);
  f16* Wg2hp = alloch((size_t)3 * HID * HID);
  f16* Wmgip = alloch((size_t)3 * HID * HID);
  f16* Wmghp = alloch((size_t)3 * HID * HID);
  f16* Wl2p  = alloch((size_t)HID * OUTD);
  f16* OUTaPF = alloch(PFG);
  f16* OUTbPF = alloch(PFG);
  f16* HMp    = alloch(PFG);
  float* T1   = alloc((size_t)178 * HID);
  float* Te   = alloc((size_t)18 * HID);
  float* xr   = alloc(NN);
  float* sS   = alloc(NN);
  float* sD   = alloc(NN);
  float* mxN  = alloc(NN);
  float* sumN = alloc(NN);
  float* aN   = alloc(NN);
  float* a_node = alloc(NN);
  float* aE   = alloc(NE);
  float* mxG  = alloc(NG);
  float* sumG = alloc(NG);
  float* a_g  = alloc(NG);
  float* OUTa = alloc(GB);
  float* OUTb = alloc(GB);
  float* GM   = alloc(GB);
  float* HM   = alloc(GB);
  (void)n_in; (void)in_sizes; (void)out_size;
  if (ws_size < off * sizeof(float)) return;  // fail loud, not with a GPU fault

  const int* dstArr = edge_index + NE;
  dim3 blk(256);
  auto g1 = [](long n) { return dim3((unsigned)((n + 255) / 256)); };
  auto gw = [](long waves) { return dim3((unsigned)((waves * 64 + 255) / 256)); };
  const long NBt = (long)NB, EBt = (long)NE * HID, GBt = (long)GB;
  // 1D XCD-grouped grids for the MFMA kernels
  const int MtH = (NN + 127) / 128;                       // 235
  const dim3 gH((unsigned)(8 * 3 * ((MtH + 7) / 8)));     // 720
  const int MtR = (NN + 63) / 64;                         // 469
  const dim3 gR((unsigned)(8 * 6 * ((MtR + 7) / 8)));     // 2832
  const int MtGH = (NG + 127) / 128;                      // 10
  const dim3 gGM((unsigned)(8 * 3 * ((MtGH + 7) / 8)));   // 48   (Nn=HID)
  const dim3 gF((unsigned)(8 * 6 * ((MtGH + 7) / 8)));    // 96   (Nn=OUTD)
  const int MtGR = (NG + 63) / 64;                        // 19
  const dim3 gRG((unsigned)(8 * 6 * ((MtGR + 7) / 8)));   // 144

  // ---- weight prep: f16 PF-packed copies ----
  hipLaunchKernelGGL(k_wpack, g1((long)HID * HID), blk, 0, stream, gl1_W, W1p, HID, HID);
  hipLaunchKernelGGL(k_wpack, g1((long)HID * HID), blk, 0, stream, gl2_W, W2p, HID, HID);
  hipLaunchKernelGGL(k_wpack, g1((long)HID * HID), blk, 0, stream, gat_W, Wgatp, HID, HID);
  hipLaunchKernelGGL(k_wpack, g1((long)HID * HID), blk, 0, stream, mol_W, Wmolp, HID, HID);
  hipLaunchKernelGGL(k_wpack, g1((long)3 * HID * HID), blk, 0, stream, gru1_Wi, Wg1ip, HID, 3 * HID);
  hipLaunchKernelGGL(k_wpack, g1((long)3 * HID * HID), blk, 0, stream, gru1_Wh, Wg1hp, HID, 3 * HID);
  hipLaunchKernelGGL(k_wpack, g1((long)3 * HID * HID), blk, 0, stream, gru2_Wi, Wg2ip, HID, 3 * HID);
  hipLaunchKernelGGL(k_wpack, g1((long)3 * HID * HID), blk, 0, stream, gru2_Wh, Wg2hp, HID, 3 * HID);
  hipLaunchKernelGGL(k_wpack, g1((long)3 * HID * HID), blk, 0, stream, mgru_Wi, Wmgip, HID, 3 * HID);
  hipLaunchKernelGGL(k_wpack, g1((long)3 * HID * HID), blk, 0, stream, mgru_Wh, Wmghp, HID, 3 * HID);
  hipLaunchKernelGGL(k_wpack, g1((long)HID * OUTD), blk, 0, stream, lin2_W, Wl2p, HID, OUTD);

  // ---- tables ----
  hipLaunchKernelGGL(k_gemm, dim3(HID / 64, 3), blk, 0, stream,
                     x_emb, lin1_W, nullptr, T1, 178, HID, EMB, 0);
  hipLaunchKernelGGL(k_gemm, dim3(HID / 64, 1), blk, 0, stream,
                     e_emb, gl1_W + (size_t)HID * HID, nullptr, Te, 18, HID, EMB, 0);

  // ---- x1 ----
  hipLaunchKernelGGL(k_node_embed, g1(NBt), blk, 0, stream, x_idx, T1, lin1_b, A, H1, NBt);

  // ---- GATEConv ----
  hipLaunchKernelGGL(k_hgemm, gH, blk, 0, stream, H1, W1p, nullptr, B, (f16*)nullptr, NN, HID, 0); // P
  hipLaunchKernelGGL(k_rowdot, gw(NN), blk, 0, stream, A, att_r, xr, NN);
  hipMemsetAsync(mxN, 0xFF, NN * sizeof(float), stream);
  hipLaunchKernelGGL(k_gate_att, gw(NE), blk, 0, stream, B, Te, edge_index, eai, att_l, xr, aE, mxN, NE);
  hipMemsetAsync(sumN, 0, NN * sizeof(float), stream);
  hipLaunchKernelGGL(k_seg_exp, g1(NE), blk, 0, stream, aE, dstArr, mxN, sumN, NE);
  hipMemsetAsync(C, 0, NB * sizeof(float), stream);
  hipLaunchKernelGGL(k_scatter_edge, g1(EBt), blk, 0, stream, B, Te, edge_index, eai, aE, sumN, C, EBt);
  hipLaunchKernelGGL(k_f2h_pf, g1(NBt), blk, 0, stream, C, H2, NBt);
  hipLaunchKernelGGL(k_hgemm, gH, blk, 0, stream, H2, W2p, gate_b, (float*)nullptr, H3, NN, HID, 2); // elu(h)
  // GRU1: x2 -> C (f32) + H2 (f16 PF)
  hipLaunchKernelGGL(k_gru_hgemm, gR, blk, 0, stream, H3, H1, A, Wg1ip, Wg1hp, gru1_bi, gru1_bh, C, H2, NN);

  // ---- GAT layer ----
  hipLaunchKernelGGL(k_hgemm, gH, blk, 0, stream, H2, Wgatp, nullptr, B, (f16*)nullptr, NN, HID, 0); // XL
  hipLaunchKernelGGL(k_rowdot2, gw(NN), blk, 0, stream, B, gat_as, gat_ad, sS, sD, NN);
  hipMemsetAsync(mxN, 0xFF, NN * sizeof(float), stream);
  hipLaunchKernelGGL(k_gat_att, g1(NE), blk, 0, stream, sS, sD, edge_index, aE, mxN, NE);
  hipMemsetAsync(sumN, 0, NN * sizeof(float), stream);
  hipLaunchKernelGGL(k_seg_exp, g1(NE), blk, 0, stream, aE, dstArr, mxN, sumN, NE);
  hipMemsetAsync(A, 0, NB * sizeof(float), stream);
  hipLaunchKernelGGL(k_scatter_gat, g1(EBt), blk, 0, stream, B, aE, sumN, edge_index, A, EBt);
  hipLaunchKernelGGL(k_bias_act, g1(NBt), blk, 0, stream, A, gat_b, H1, NBt, 2); // A=elu, H1=PF
  // GRU2: x3 -> B (f32) + H3 (f16 PF)
  hipLaunchKernelGGL(k_gru_hgemm, gR, blk, 0, stream, H1, H2, C, Wg2ip, Wg2hp, gru2_bi, gru2_bh, B, H3, NN);

  // ---- molecule readout ----
  hipMemsetAsync(OUTa, 0, GB * sizeof(float), stream);
  hipLaunchKernelGGL(k_scatter_sum, g1(NBt), blk, 0, stream, B, batch, OUTa, NBt);
  hipLaunchKernelGGL(k_bias_act, g1(GBt), blk, 0, stream, OUTa, (const float*)nullptr, OUTaPF, GBt, 3);
  hipLaunchKernelGGL(k_hgemm, gH, blk, 0, stream, H3, Wmolp, nullptr, A, (f16*)nullptr, NN, HID, 0); // XLm
  hipLaunchKernelGGL(k_rowdot, gw(NN), blk, 0, stream, A, mol_as, a_node, NN);

  float* cur = OUTa;   f16* curPF = OUTaPF;
  float* nxt = OUTb;   f16* nxtPF = OUTbPF;
  for (int t = 0; t < 3; t++) {
    hipLaunchKernelGGL(k_hgemm, gGM, blk, 0, stream, curPF, Wmolp, nullptr, GM, (f16*)nullptr, NG, HID, 0);
    hipLaunchKernelGGL(k_rowdot, gw(NG), blk, 0, stream, GM, mol_ad, a_g, NG);
    hipMemsetAsync(mxG, 0xFF, NG * sizeof(float), stream);
    hipLaunchKernelGGL(k_mol_att, g1(NN), blk, 0, stream, a_node, a_g, batch, aN, mxG, NN);
    hipMemsetAsync(sumG, 0, NG * sizeof(float), stream);
    hipLaunchKernelGGL(k_seg_exp, g1(NN), blk, 0, stream, aN, batch, mxG, sumG, NN);
    hipMemsetAsync(HM, 0, GB * sizeof(float), stream);
    hipLaunchKernelGGL(k_scatter_node, g1(NBt), blk, 0, stream, A, aN, sumG, batch, HM, NBt);
    hipLaunchKernelGGL(k_bias_act, g1(GBt), blk, 0, stream, HM, mol_b, HMp, GBt, 2);
    hipLaunchKernelGGL(k_gru_hgemm, gRG, blk, 0, stream, HMp, curPF, cur,
                       Wmgip, Wmghp, mgru_bi, mgru_bh, nxt, nxtPF, NG);
    float* tf = cur; cur = nxt; nxt = tf;
    f16* th = curPF; curPF = nxtPF; nxtPF = th;
  }

  // ---- final projection: out = cur @ lin2_W + lin2_b ----
  hipLaunchKernelGGL(k_hgemm, gF, blk, 0, stream, curPF, Wl2p, lin2_b, outp, (f16*)nullptr, NG, OUTD, 0);
}